// Round 3
// baseline (275.231 us; speedup 1.0000x reference)
//
#include <hip/hip_runtime.h>
#include <math.h>

typedef float f32x4 __attribute__((ext_vector_type(4)));
typedef short s16x8 __attribute__((ext_vector_type(8)));
typedef unsigned int u32;
typedef unsigned short u16;
typedef u16 u16x4 __attribute__((ext_vector_type(4)));

// ---------------- ws layout (float offsets) ---------------------------------
// Base 58.5 MB layout (R8-proven):
//   XQ region [4734976,8929280): xq bf16 (prep..sim) -> attnT bf16 at 4734976
//     (finish..gemm1) + wattn bf16 at 6832128 (gemm1..gemm2)
//   P region [8929280,13123584): p0/p1 bf16 (sim..finish) -> vT (fallback only)
// Roomy path (ws >= 75.3 MB): vT moves to fresh space at OFF_VT2 so conv can
//   run CONCURRENTLY with sim (p0/p1 stay live until finish).
static constexpr size_t OFF_XT    = 0;          // bf16 [16,1156,512]
static constexpr size_t OFF_XQ    = 4734976;
static constexpr size_t OFF_ATTNT = 4734976;    // after xq dies
static constexpr size_t OFF_WATTN = 6832128;
static constexpr size_t OFF_P0    = 8929280;    // bf16 [16,512,512]
static constexpr size_t OFF_P1    = 11026432;   // bf16 [16,512,512]
static constexpr size_t OFF_VT    = 8929280;    // fallback: after p0/p1 die
static constexpr size_t OFF_WA    = 13123584;   // bf16 [512,4608]
static constexpr size_t OFF_RM    = 14303232;   // f32 [512,512]
static constexpr size_t OFF_WWB   = 14565376;   // bf16 [256,512]
static constexpr size_t OFF_VT2   = 14630912;   // bf16 [16,1024,512] (roomy path)
// roomy end: 14630912*4 + 16777216 = 75,300,864 B

__device__ __forceinline__ u16 f2bf(float f) {
    u32 u = __float_as_uint(f);
    u32 r = (u + 0x7FFFu + ((u >> 16) & 1u)) >> 16;   // RNE
    return (u16)r;
}
__device__ __forceinline__ float bf2f(u16 v) {
    return __uint_as_float(((u32)v) << 16);
}

__device__ __forceinline__ void gload_lds16(const void* g, void* l) {
    __builtin_amdgcn_global_load_lds(
        (const u32 __attribute__((address_space(1)))*)(uintptr_t)g,
        (u32 __attribute__((address_space(3)))*)(uintptr_t)l, 16, 0, 0);
}

// ================================================================ PREP (R6/R8-proven)
__global__ __launch_bounds__(256) void prep_kernel(const float* __restrict__ x1,
                                                   const float* __restrict__ x2,
                                                   const float* __restrict__ gw,
                                                   const float* __restrict__ ww,
                                                   const float* __restrict__ w1,
                                                   const float* __restrict__ w2,
                                                   float* __restrict__ rm,
                                                   u16* __restrict__ wA,
                                                   u16* __restrict__ wwb,
                                                   u16* __restrict__ xT,
                                                   u16* __restrict__ xq) {
    __shared__ __attribute__((aligned(16))) u32 shm[4608];
    const int t = threadIdx.x;
    const int bid = blockIdx.x;

    if (bid < 512) {                        // ---- gw permute-cast
        const int co = bid;
        const float* g = gw + (size_t)co * 4608;
        float* lf = (float*)shm;
#pragma unroll
        for (int i = 0; i < 18; ++i) lf[t + i * 256] = g[t + i * 256];
        __syncthreads();
        u16* dst = wA + (size_t)co * 4608;
#pragma unroll
        for (int i = 0; i < 18; ++i) {
            int k = t + i * 256;
            int r = k >> 9, ci = k & 511;
            dst[k] = f2bf(lf[ci * 9 + r]);
        }
    } else if (bid < 2560) {                // ---- x fused cast + transpose
        int xid = bid - 512;
        int nt = xid & 15;
        int cit = (xid >> 4) & 7;
        int b = xid >> 7;
        int n0 = nt * 64, ci0 = cit * 64;
        const float* src = (ci0 < 256) ? (x1 + ((size_t)(b * 256 + ci0)) * 1024)
                                       : (x2 + ((size_t)(b * 256 + ci0 - 256)) * 1024);
        u16* xqb = xq + ((size_t)(b * 512 + ci0)) * 1024;
        u16* lt = (u16*)shm;
#pragma unroll
        for (int p4 = 0; p4 < 4; ++p4) {
            int ch = (t >> 4) + p4 * 16;
            int px = (t & 15) * 4;
            float4 v = *(const float4*)&src[(size_t)ch * 1024 + n0 + px];
            u16x4 pk = {f2bf(v.x), f2bf(v.y), f2bf(v.z), f2bf(v.w)};
            *(u16x4*)&xqb[(size_t)ch * 1024 + n0 + px] = pk;
            lt[(px + 0) * 65 + ch] = pk[0];
            lt[(px + 1) * 65 + ch] = pk[1];
            lt[(px + 2) * 65 + ch] = pk[2];
            lt[(px + 3) * 65 + ch] = pk[3];
        }
        __syncthreads();
        {
            int px_l = t >> 2, c16 = (t & 3) * 16;
            int n = n0 + px_l;
            int y = n >> 5, x = n & 31;
            int p = (y + 1) * 34 + (x + 1);
            u16* dst = xT + ((size_t)b * 1156 + p) * 512 + ci0 + c16;
            *(s16x8*)&dst[0] = *(const s16x8*)&lt[px_l * 65 + c16];
            *(s16x8*)&dst[8] = *(const s16x8*)&lt[px_l * 65 + c16 + 8];
        }
    } else if (bid < 2576) {                // ---- border zero
        int b = bid - 2560;
        u16* base = xT + (size_t)b * 1156 * 512;
        s16x8 z = {0, 0, 0, 0, 0, 0, 0, 0};
        for (int idx = t; idx < 132 * 64; idx += 256) {
            int row = idx >> 6, seg = idx & 63;
            int p;
            if (row < 34) p = row;
            else if (row < 68) p = 1122 + (row - 34);
            else if (row < 100) p = (row - 67) * 34;
            else p = (row - 99) * 34 + 33;
            *(s16x8*)&base[(size_t)p * 512 + seg * 8] = z;
        }
    } else if (bid < 3600) {                // ---- rm
        int idx = (bid - 2576) * 256 + t;
        int c = idx >> 9, d = idx & 511;
        float s = 0.f;
#pragma unroll
        for (int k = 0; k < 16; ++k) s = fmaf(w1[c * 16 + k], w2[d * 16 + k], s);
        rm[idx] = s;
    } else {                                // ---- wwb cast
        int idx = (bid - 3600) * 256 + t;
        float4 v = ((const float4*)ww)[idx];
        u16x4 pk = {f2bf(v.x), f2bf(v.y), f2bf(v.z), f2bf(v.w)};
        *(u16x4*)&wwb[(size_t)idx * 4] = pk;
    }
}

// ================================================================ SIM body (proven)
// pK[b][d][c] = bf16( sum_{k in half} xq[c][k]*xq[d][k] )   128x128 tile, BK=64
// bx: x&3 = d-tile, x>>2 = khalf; by = c-tile; bz = b.
__device__ __forceinline__ void sim_body(u16* __restrict__ smem,
                                         const u16* __restrict__ xq,
                                         u16* __restrict__ simP,
                                         int bx, int by, int bz) {
    u16* As = smem;
    u16* Bs = smem + 128 * 64;
    const int b = bz, m0 = by * 128;
    const int n0 = (bx & 3) * 128, khalf = bx >> 2;
    const int t = threadIdx.x, w = t >> 6, l = t & 63;
    const u16* xb = xq + (size_t)b * 512 * 1024 + khalf * 512;

    const u16 *agp[4], *bgp[4];
    u16 *ald[4], *bld[4];
#pragma unroll
    for (int i = 0; i < 4; ++i) {
        int rr = w * 8 + i * 32 + (l >> 3);
        int gi = (l & 7) ^ (rr & 7);
        agp[i] = xb + (size_t)(m0 + rr) * 1024 + gi * 8;
        bgp[i] = xb + (size_t)(n0 + rr) * 1024 + gi * 8;
        ald[i] = &As[(w * 8 + i * 32) * 64];
        bld[i] = &Bs[(w * 8 + i * 32) * 64];
    }

    f32x4 acc[4][4] = {};
    const int wm = (w >> 1) * 64, wn = (w & 1) * 64;

    for (int kt = 0; kt < 8; ++kt) {
        int ko = kt << 6;
        if (kt) __syncthreads();
#pragma unroll
        for (int i = 0; i < 4; ++i) gload_lds16(agp[i] + ko, ald[i]);
#pragma unroll
        for (int i = 0; i < 4; ++i) gload_lds16(bgp[i] + ko, bld[i]);
        __syncthreads();
#pragma unroll
        for (int kk = 0; kk < 2; ++kk) {
            int gbase = kk * 4 + (l >> 4);
            s16x8 af[4], bf[4];
#pragma unroll
            for (int i = 0; i < 4; ++i) {
                int row = wm + i * 16 + (l & 15);
                af[i] = *(const s16x8*)&As[row * 64 + ((gbase ^ (row & 7)) << 3)];
            }
#pragma unroll
            for (int j = 0; j < 4; ++j) {
                int row = wn + j * 16 + (l & 15);
                bf[j] = *(const s16x8*)&Bs[row * 64 + ((gbase ^ (row & 7)) << 3)];
            }
#pragma unroll
            for (int i = 0; i < 4; ++i)
#pragma unroll
                for (int j = 0; j < 4; ++j)
                    acc[i][j] = __builtin_amdgcn_mfma_f32_16x16x32_bf16(af[i], bf[j], acc[i][j], 0, 0, 0);
        }
    }

    // transposed bf16 store [d][c] (proven epilogue)
    __syncthreads();
    const int col = l & 15, r4 = (l >> 4) * 4;
#pragma unroll
    for (int i = 0; i < 4; ++i)
#pragma unroll
        for (int j = 0; j < 4; ++j) {
            int n_l = wn + j * 16 + col;
            int m_b = wm + i * 16 + r4;
            u16x4 pk = {f2bf(acc[i][j][0]), f2bf(acc[i][j][1]),
                        f2bf(acc[i][j][2]), f2bf(acc[i][j][3])};
            *(u16x4*)&smem[n_l * 128 + (m_b ^ ((n_l & 15) << 3))] = pk;
        }
    __syncthreads();
    u16* sTb = simP + (size_t)khalf * 4194304 + (size_t)b * 512 * 512;
    {
        int n_l = t >> 1;
#pragma unroll
        for (int rep = 0; rep < 8; ++rep) {
            int c0 = (((t & 1) + rep * 2) << 3);
            s16x8 v = *(const s16x8*)&smem[n_l * 128 + (c0 ^ ((n_l & 15) << 3))];
            *(s16x8*)&sTb[(size_t)(n0 + n_l) * 512 + m0 + c0] = v;
        }
    }
}

// ================================================================ CONV body (proven)
// bx = n-tile (8), by = m-tile (4), bz = b.
__device__ __forceinline__ void conv_body(u16* __restrict__ smem,
                                          const u16* __restrict__ wA,
                                          const u16* __restrict__ xT,
                                          u16* __restrict__ vT,
                                          int bx, int by, int bz) {
    u16* As = smem;
    u16* Bs = smem + 128 * 64;
    const int b = bz, m0 = by * 128, n0 = bx * 128;
    const int t = threadIdx.x, w = t >> 6, l = t & 63;
    const u16* xTb = xT + (size_t)b * 1156 * 512;

    int gi[4], pb[4];
    const u16* agp[4];
    u16 *ald[4], *bld[4];
#pragma unroll
    for (int i = 0; i < 4; ++i) {
        int rr = w * 8 + i * 32 + (l >> 3);
        gi[i] = (l & 7) ^ (rr & 7);
        agp[i] = wA + (size_t)(m0 + rr) * 4608 + gi[i] * 8;
        int n = n0 + rr;
        pb[i] = (n >> 5) * 34 + (n & 31);
        ald[i] = &As[(w * 8 + i * 32) * 64];
        bld[i] = &Bs[(w * 8 + i * 32) * 64];
    }

    f32x4 acc[4][4] = {};
    const int wm = (w >> 1) * 64, wn = (w & 1) * 64;

    for (int kt = 0; kt < 72; ++kt) {
        int r = kt >> 3, ci0k = (kt & 7) << 6;
        int rdiv3 = (r * 11) >> 5;
        int poff = rdiv3 * 34 + (r - rdiv3 * 3);
        int aofs = r * 512 + ci0k;
        if (kt) __syncthreads();
#pragma unroll
        for (int i = 0; i < 4; ++i) gload_lds16(agp[i] + aofs, ald[i]);
#pragma unroll
        for (int i = 0; i < 4; ++i)
            gload_lds16(xTb + (size_t)(pb[i] + poff) * 512 + ci0k + gi[i] * 8, bld[i]);
        __syncthreads();

#pragma unroll
        for (int kk = 0; kk < 2; ++kk) {
            int gbase = kk * 4 + (l >> 4);
            s16x8 af[4], bf[4];
#pragma unroll
            for (int i = 0; i < 4; ++i) {
                int row = wm + i * 16 + (l & 15);
                af[i] = *(const s16x8*)&As[row * 64 + ((gbase ^ (row & 7)) << 3)];
            }
#pragma unroll
            for (int j = 0; j < 4; ++j) {
                int row = wn + j * 16 + (l & 15);
                bf[j] = *(const s16x8*)&Bs[row * 64 + ((gbase ^ (row & 7)) << 3)];
            }
#pragma unroll
            for (int i = 0; i < 4; ++i)
#pragma unroll
                for (int j = 0; j < 4; ++j)
                    acc[i][j] = __builtin_amdgcn_mfma_f32_16x16x32_bf16(af[i], bf[j], acc[i][j], 0, 0, 0);
        }
    }

    __syncthreads();
    const int col = l & 15, r4 = (l >> 4) * 4;
#pragma unroll
    for (int i = 0; i < 4; ++i)
#pragma unroll
        for (int j = 0; j < 4; ++j) {
            int n_l = wn + j * 16 + col;
            int co_b = wm + i * 16 + r4;
            u16x4 pk = {f2bf(acc[i][j][0]), f2bf(acc[i][j][1]),
                        f2bf(acc[i][j][2]), f2bf(acc[i][j][3])};
            *(u16x4*)&smem[n_l * 128 + (co_b ^ ((n_l & 15) << 3))] = pk;
        }
    __syncthreads();
    u16* vTb = vT + (size_t)b * 1024 * 512;
    {
        int n_l = t >> 1;
#pragma unroll
        for (int rep = 0; rep < 8; ++rep) {
            int c0 = (((t & 1) + rep * 2) << 3);
            s16x8 v = *(const s16x8*)&smem[n_l * 128 + (c0 ^ ((n_l & 15) << 3))];
            *(s16x8*)&vTb[(size_t)(n0 + n_l) * 512 + m0 + c0] = v;
        }
    }
}

// ---- standalone kernels (fallback path, byte-identical behavior) ----
__global__ __launch_bounds__(256) void sim_part(const u16* __restrict__ xq,
                                                u16* __restrict__ simP) {
    __shared__ __attribute__((aligned(16))) u16 smem[128 * 128];
    sim_body(smem, xq, simP, blockIdx.x, blockIdx.y, blockIdx.z);
}
__global__ __launch_bounds__(256) void conv_gemm(const u16* __restrict__ wA,
                                                 const u16* __restrict__ xT,
                                                 u16* __restrict__ vT) {
    __shared__ __attribute__((aligned(16))) u16 smem[128 * 128];
    conv_body(smem, wA, xT, vT, blockIdx.x, blockIdx.y, blockIdx.z);
}

// ---- fused: conv (x<8) || sim (x>=8), 1024 blocks, shared 32 KB LDS ----
// Legal only when vT does NOT alias p0/p1 (roomy ws path): sim writes p0/p1
// while conv writes vT concurrently; finish reads p0/p1 afterwards.
__global__ __launch_bounds__(256) void sim_conv_fused(const u16* __restrict__ xq,
                                                      u16* __restrict__ simP,
                                                      const u16* __restrict__ wA,
                                                      const u16* __restrict__ xT,
                                                      u16* __restrict__ vT) {
    __shared__ __attribute__((aligned(16))) u16 smem[128 * 128];
    if (blockIdx.x < 8)
        conv_body(smem, wA, xT, vT, blockIdx.x, blockIdx.y, blockIdx.z);
    else
        sim_body(smem, xq, simP, blockIdx.x - 8, blockIdx.y, blockIdx.z);
}

// ================================================================ FINISH (single-pass, e[] in regs)
__global__ __launch_bounds__(256) void finish_kernel(const u16* __restrict__ p0,
                                                     const u16* __restrict__ p1,
                                                     const float* __restrict__ rm,
                                                     u16* __restrict__ attnT) {
    __shared__ float rml[32 * 513];   // rm rows c0..c0+31, stride 513 (conflict-free)
    __shared__ float scr[256];
    const int t = threadIdx.x;
    const int b = blockIdx.x >> 4, c0 = (blockIdx.x & 15) * 32;
    const int cl = t & 31, g = t >> 5;
    const float scale = 0.04419417382415922f;   // 512^-0.5

    for (int idx = t; idx < 32 * 512; idx += 256) {
        int c_l = idx >> 9, d = idx & 511;
        rml[c_l * 513 + d] = rm[(size_t)(c0 + c_l) * 512 + d];
    }
    __syncthreads();

    const u16* q0 = p0 + (size_t)b * 262144 + c0 + cl;
    const u16* q1 = p1 + (size_t)b * 262144 + c0 + cl;
    u16* ap = attnT + (size_t)b * 262144 + c0 + cl;
    const float* rp = &rml[cl * 513];

    float e[64];
    float s = 0.f;
#pragma unroll
    for (int dd = 0; dd < 64; ++dd) {
        int d = g * 64 + dd;
        float v = (bf2f(q0[(size_t)d * 512]) + bf2f(q1[(size_t)d * 512])) * scale + rp[d];
        e[dd] = __expf(v);
        s += e[dd];
    }
    scr[t] = s;
    __syncthreads();
    float tot = 0.f;
#pragma unroll
    for (int k = 0; k < 8; ++k) tot += scr[k * 32 + cl];
    float inv = 1.f / tot;
#pragma unroll
    for (int dd = 0; dd < 64; ++dd) {
        int d = g * 64 + dd;
        ap[(size_t)d * 512] = f2bf(e[dd] * inv);
    }
}

// ================================================================ generic bf16 MFMA NT GEMM (proven)
// MODE 1: bf16 out (wattn); MODE 2: f32 out (final)
template <int MODE>
__global__ __launch_bounds__(256) void gemm_nt(const u16* __restrict__ A, size_t sA,
                                               const u16* __restrict__ B, size_t sB,
                                               void* __restrict__ Cv, size_t sC,
                                               int K, int ldc) {
    __shared__ __attribute__((aligned(16))) u16 As[128 * 64];
    __shared__ __attribute__((aligned(16))) u16 Bs[128 * 64];
    const int b = blockIdx.z, m0 = blockIdx.y * 128, n0 = blockIdx.x * 128;
    const int t = threadIdx.x, w = t >> 6, l = t & 63;
    const u16* Ab = A + (size_t)b * sA;
    const u16* Bb = B + (size_t)b * sB;

    const u16 *agp[4], *bgp[4];
    u16 *ald[4], *bld[4];
#pragma unroll
    for (int i = 0; i < 4; ++i) {
        int rr = w * 8 + i * 32 + (l >> 3);
        int gi = (l & 7) ^ (rr & 7);
        agp[i] = Ab + (size_t)(m0 + rr) * K + gi * 8;
        bgp[i] = Bb + (size_t)(n0 + rr) * K + gi * 8;
        ald[i] = &As[(w * 8 + i * 32) * 64];
        bld[i] = &Bs[(w * 8 + i * 32) * 64];
    }

    f32x4 acc[4][4] = {};
    const int wm = (w >> 1) * 64, wn = (w & 1) * 64;
    const int nkt = K >> 6;
    for (int kt = 0; kt < nkt; ++kt) {
        int ko = kt << 6;
        if (kt) __syncthreads();
#pragma unroll
        for (int i = 0; i < 4; ++i) gload_lds16(agp[i] + ko, ald[i]);
#pragma unroll
        for (int i = 0; i < 4; ++i) gload_lds16(bgp[i] + ko, bld[i]);
        __syncthreads();
#pragma unroll
        for (int kk = 0; kk < 2; ++kk) {
            int gbase = kk * 4 + (l >> 4);
            s16x8 af[4], bf[4];
#pragma unroll
            for (int i = 0; i < 4; ++i) {
                int row = wm + i * 16 + (l & 15);
                af[i] = *(const s16x8*)&As[row * 64 + ((gbase ^ (row & 7)) << 3)];
            }
#pragma unroll
            for (int j = 0; j < 4; ++j) {
                int row = wn + j * 16 + (l & 15);
                bf[j] = *(const s16x8*)&Bs[row * 64 + ((gbase ^ (row & 7)) << 3)];
            }
#pragma unroll
            for (int i = 0; i < 4; ++i)
#pragma unroll
                for (int j = 0; j < 4; ++j)
                    acc[i][j] = __builtin_amdgcn_mfma_f32_16x16x32_bf16(af[i], bf[j], acc[i][j], 0, 0, 0);
        }
    }

    const int col = l & 15, r4 = (l >> 4) * 4;
#pragma unroll
    for (int i = 0; i < 4; ++i)
#pragma unroll
        for (int j = 0; j < 4; ++j)
#pragma unroll
            for (int reg = 0; reg < 4; ++reg) {
                int m = m0 + wm + i * 16 + r4 + reg;
                int n = n0 + wn + j * 16 + col;
                if (MODE == 1) {
                    u16* C = (u16*)Cv + (size_t)b * sC;
                    C[(size_t)m * ldc + n] = f2bf(acc[i][j][reg]);
                } else {
                    float* C = (float*)Cv + (size_t)b * sC;
                    C[(size_t)m * ldc + n] = acc[i][j][reg];
                }
            }
}

// ----------------------------------------------------------------
extern "C" void kernel_launch(void* const* d_in, const int* in_sizes, int n_in,
                              void* d_out, int out_size, void* d_ws, size_t ws_size,
                              hipStream_t stream) {
    (void)in_sizes; (void)n_in; (void)out_size;
    const float* x1 = (const float*)d_in[0];
    const float* x2 = (const float*)d_in[1];
    const float* gw = (const float*)d_in[2];
    const float* ww = (const float*)d_in[3];
    const float* w1 = (const float*)d_in[4];
    const float* w2 = (const float*)d_in[5];
    float* out = (float*)d_out;
    float* ws = (float*)d_ws;

    u16* xT    = (u16*)(ws + OFF_XT);
    u16* xq    = (u16*)(ws + OFF_XQ);
    u16* attnT = (u16*)(ws + OFF_ATTNT);   // after xq dies
    u16* wattn = (u16*)(ws + OFF_WATTN);
    u16* simP  = (u16*)(ws + OFF_P0);      // p0; p1 at +4,194,304 u16
    u16* p0    = (u16*)(ws + OFF_P0);
    u16* p1    = (u16*)(ws + OFF_P1);
    u16* wA    = (u16*)(ws + OFF_WA);
    float* rm  = ws + OFF_RM;
    u16* wwb   = (u16*)(ws + OFF_WWB);

    // roomy: vT in fresh space past 58.5 MB -> conv can overlap sim.
    const bool roomy = ws_size >= (size_t)75300864;
    u16* vT = roomy ? (u16*)(ws + OFF_VT2) : (u16*)(ws + OFF_VT);

    prep_kernel<<<3728, 256, 0, stream>>>(x1, x2, gw, ww, w1, w2, rm, wA, wwb, xT, xq);

    if (roomy) {
        // conv (x<8) runs concurrently with sim (x>=8): 1024 blocks, 4/CU,
        // sim's VMEM/VALU fills conv's barrier-drain idle (m114 co-scheduling).
        sim_conv_fused<<<dim3(16, 4, 16), 256, 0, stream>>>(xq, simP, wA, xT, vT);
    } else {
        sim_part<<<dim3(8, 4, 16), 256, 0, stream>>>(xq, simP);
    }

    // attnT[b][d][c] = softmax over d of ((p0+p1)*scale + rm[c][d])
    finish_kernel<<<256, 256, 0, stream>>>(p0, p1, rm, attnT);
    // wattn[b][o][d] = sum_c wwb[o][c] * attnT[b][d][c]  (bf16 out)
    gemm_nt<1><<<dim3(4, 2, 16), 256, 0, stream>>>(
        wwb, 0, attnT, (size_t)512 * 512, wattn, (size_t)256 * 512, 512, 512);

    if (!roomy)
        conv_gemm<<<dim3(8, 4, 16), 256, 0, stream>>>(wA, xT, vT);

    // out[b][o][n] = sum_d wattn[b][o][d] * vT[b][n][d]  (f32 out)
    gemm_nt<2><<<dim3(8, 2, 16), 256, 0, stream>>>(
        wattn, (size_t)256 * 512, vT, (size_t)1024 * 512, out, (size_t)256 * 1024, 512, 1024);
}

// Round 4
// 238.871 us; speedup vs baseline: 1.1522x; 1.1522x over previous
//
#include <hip/hip_runtime.h>
#include <math.h>

typedef float f32x4 __attribute__((ext_vector_type(4)));
typedef short s16x8 __attribute__((ext_vector_type(8)));
typedef unsigned int u32;
typedef unsigned short u16;
typedef u16 u16x4 __attribute__((ext_vector_type(4)));

// ---------------- ws layout (float offsets) ---------------------------------
// Base 58.5 MB layout (R8-proven):
//   XQ region [4734976,8929280): xq bf16 (prep..sim) -> attnT bf16 at 4734976
//     (finish..gemm1) + wattn bf16 at 6832128 (gemm1..gemm2)
//   P region [8929280,13123584): p0/p1 bf16 (sim..finish) -> vT0 (conv..gemm2)
// Split-K path (ws >= 75.3 MB, PROVEN present in R3): vT1 partial at OFF_VT2.
static constexpr size_t OFF_XT    = 0;          // bf16 [16,1156,512]
static constexpr size_t OFF_XQ    = 4734976;
static constexpr size_t OFF_ATTNT = 4734976;    // after xq dies
static constexpr size_t OFF_WATTN = 6832128;
static constexpr size_t OFF_P0    = 8929280;    // bf16 [16,512,512]
static constexpr size_t OFF_P1    = 11026432;   // bf16 [16,512,512]
static constexpr size_t OFF_VT    = 8929280;    // vT0: after p0/p1 die
static constexpr size_t OFF_WA    = 13123584;   // bf16 [512,4608]
static constexpr size_t OFF_RM    = 14303232;   // f32 [512,512]
static constexpr size_t OFF_WWB   = 14565376;   // bf16 [256,512]
static constexpr size_t OFF_VT2   = 14630912;   // bf16 [16,1024,512] (split-K vT1)
// split-K end: 14630912*4 + 16777216 = 75,300,864 B (== R3-proven bound)

__device__ __forceinline__ u16 f2bf(float f) {
    u32 u = __float_as_uint(f);
    u32 r = (u + 0x7FFFu + ((u >> 16) & 1u)) >> 16;   // RNE
    return (u16)r;
}
__device__ __forceinline__ float bf2f(u16 v) {
    return __uint_as_float(((u32)v) << 16);
}

__device__ __forceinline__ void gload_lds16(const void* g, void* l) {
    __builtin_amdgcn_global_load_lds(
        (const u32 __attribute__((address_space(1)))*)(uintptr_t)g,
        (u32 __attribute__((address_space(3)))*)(uintptr_t)l, 16, 0, 0);
}

// ================================================================ PREP (R6/R8-proven)
__global__ __launch_bounds__(256) void prep_kernel(const float* __restrict__ x1,
                                                   const float* __restrict__ x2,
                                                   const float* __restrict__ gw,
                                                   const float* __restrict__ ww,
                                                   const float* __restrict__ w1,
                                                   const float* __restrict__ w2,
                                                   float* __restrict__ rm,
                                                   u16* __restrict__ wA,
                                                   u16* __restrict__ wwb,
                                                   u16* __restrict__ xT,
                                                   u16* __restrict__ xq) {
    __shared__ __attribute__((aligned(16))) u32 shm[4608];
    const int t = threadIdx.x;
    const int bid = blockIdx.x;

    if (bid < 512) {                        // ---- gw permute-cast
        const int co = bid;
        const float* g = gw + (size_t)co * 4608;
        float* lf = (float*)shm;
#pragma unroll
        for (int i = 0; i < 18; ++i) lf[t + i * 256] = g[t + i * 256];
        __syncthreads();
        u16* dst = wA + (size_t)co * 4608;
#pragma unroll
        for (int i = 0; i < 18; ++i) {
            int k = t + i * 256;
            int r = k >> 9, ci = k & 511;
            dst[k] = f2bf(lf[ci * 9 + r]);
        }
    } else if (bid < 2560) {                // ---- x fused cast + transpose
        int xid = bid - 512;
        int nt = xid & 15;
        int cit = (xid >> 4) & 7;
        int b = xid >> 7;
        int n0 = nt * 64, ci0 = cit * 64;
        const float* src = (ci0 < 256) ? (x1 + ((size_t)(b * 256 + ci0)) * 1024)
                                       : (x2 + ((size_t)(b * 256 + ci0 - 256)) * 1024);
        u16* xqb = xq + ((size_t)(b * 512 + ci0)) * 1024;
        u16* lt = (u16*)shm;
#pragma unroll
        for (int p4 = 0; p4 < 4; ++p4) {
            int ch = (t >> 4) + p4 * 16;
            int px = (t & 15) * 4;
            float4 v = *(const float4*)&src[(size_t)ch * 1024 + n0 + px];
            u16x4 pk = {f2bf(v.x), f2bf(v.y), f2bf(v.z), f2bf(v.w)};
            *(u16x4*)&xqb[(size_t)ch * 1024 + n0 + px] = pk;
            lt[(px + 0) * 65 + ch] = pk[0];
            lt[(px + 1) * 65 + ch] = pk[1];
            lt[(px + 2) * 65 + ch] = pk[2];
            lt[(px + 3) * 65 + ch] = pk[3];
        }
        __syncthreads();
        {
            int px_l = t >> 2, c16 = (t & 3) * 16;
            int n = n0 + px_l;
            int y = n >> 5, x = n & 31;
            int p = (y + 1) * 34 + (x + 1);
            u16* dst = xT + ((size_t)b * 1156 + p) * 512 + ci0 + c16;
            *(s16x8*)&dst[0] = *(const s16x8*)&lt[px_l * 65 + c16];
            *(s16x8*)&dst[8] = *(const s16x8*)&lt[px_l * 65 + c16 + 8];
        }
    } else if (bid < 2576) {                // ---- border zero
        int b = bid - 2560;
        u16* base = xT + (size_t)b * 1156 * 512;
        s16x8 z = {0, 0, 0, 0, 0, 0, 0, 0};
        for (int idx = t; idx < 132 * 64; idx += 256) {
            int row = idx >> 6, seg = idx & 63;
            int p;
            if (row < 34) p = row;
            else if (row < 68) p = 1122 + (row - 34);
            else if (row < 100) p = (row - 67) * 34;
            else p = (row - 99) * 34 + 33;
            *(s16x8*)&base[(size_t)p * 512 + seg * 8] = z;
        }
    } else if (bid < 3600) {                // ---- rm
        int idx = (bid - 2576) * 256 + t;
        int c = idx >> 9, d = idx & 511;
        float s = 0.f;
#pragma unroll
        for (int k = 0; k < 16; ++k) s = fmaf(w1[c * 16 + k], w2[d * 16 + k], s);
        rm[idx] = s;
    } else {                                // ---- wwb cast
        int idx = (bid - 3600) * 256 + t;
        float4 v = ((const float4*)ww)[idx];
        u16x4 pk = {f2bf(v.x), f2bf(v.y), f2bf(v.z), f2bf(v.w)};
        *(u16x4*)&wwb[(size_t)idx * 4] = pk;
    }
}

// ================================================================ SIM partial GEMM (split-K, proven)
// pK[b][d][c] = bf16( sum_{k in half} xq[c][k]*xq[d][k] )   128x128 tile, BK=64
// grid (8,4,16): x&3 = d-tile, x>>2 = khalf, y = c-tile, z = b.  512 blocks (2/CU).
__global__ __launch_bounds__(256) void sim_part(const u16* __restrict__ xq,
                                                u16* __restrict__ simP) {
    __shared__ __attribute__((aligned(16))) u16 smem[128 * 128];
    u16* As = smem;
    u16* Bs = smem + 128 * 64;
    const int b = blockIdx.z, m0 = blockIdx.y * 128;
    const int n0 = (blockIdx.x & 3) * 128, khalf = blockIdx.x >> 2;
    const int t = threadIdx.x, w = t >> 6, l = t & 63;
    const u16* xb = xq + (size_t)b * 512 * 1024 + khalf * 512;

    const u16 *agp[4], *bgp[4];
    u16 *ald[4], *bld[4];
#pragma unroll
    for (int i = 0; i < 4; ++i) {
        int rr = w * 8 + i * 32 + (l >> 3);
        int gi = (l & 7) ^ (rr & 7);
        agp[i] = xb + (size_t)(m0 + rr) * 1024 + gi * 8;
        bgp[i] = xb + (size_t)(n0 + rr) * 1024 + gi * 8;
        ald[i] = &As[(w * 8 + i * 32) * 64];
        bld[i] = &Bs[(w * 8 + i * 32) * 64];
    }

    f32x4 acc[4][4] = {};
    const int wm = (w >> 1) * 64, wn = (w & 1) * 64;

    for (int kt = 0; kt < 8; ++kt) {
        int ko = kt << 6;
        if (kt) __syncthreads();
#pragma unroll
        for (int i = 0; i < 4; ++i) gload_lds16(agp[i] + ko, ald[i]);
#pragma unroll
        for (int i = 0; i < 4; ++i) gload_lds16(bgp[i] + ko, bld[i]);
        __syncthreads();
#pragma unroll
        for (int kk = 0; kk < 2; ++kk) {
            int gbase = kk * 4 + (l >> 4);
            s16x8 af[4], bf[4];
#pragma unroll
            for (int i = 0; i < 4; ++i) {
                int row = wm + i * 16 + (l & 15);
                af[i] = *(const s16x8*)&As[row * 64 + ((gbase ^ (row & 7)) << 3)];
            }
#pragma unroll
            for (int j = 0; j < 4; ++j) {
                int row = wn + j * 16 + (l & 15);
                bf[j] = *(const s16x8*)&Bs[row * 64 + ((gbase ^ (row & 7)) << 3)];
            }
#pragma unroll
            for (int i = 0; i < 4; ++i)
#pragma unroll
                for (int j = 0; j < 4; ++j)
                    acc[i][j] = __builtin_amdgcn_mfma_f32_16x16x32_bf16(af[i], bf[j], acc[i][j], 0, 0, 0);
        }
    }

    // transposed bf16 store [d][c] (proven epilogue)
    __syncthreads();
    const int col = l & 15, r4 = (l >> 4) * 4;
#pragma unroll
    for (int i = 0; i < 4; ++i)
#pragma unroll
        for (int j = 0; j < 4; ++j) {
            int n_l = wn + j * 16 + col;
            int m_b = wm + i * 16 + r4;
            u16x4 pk = {f2bf(acc[i][j][0]), f2bf(acc[i][j][1]),
                        f2bf(acc[i][j][2]), f2bf(acc[i][j][3])};
            *(u16x4*)&smem[n_l * 128 + (m_b ^ ((n_l & 15) << 3))] = pk;
        }
    __syncthreads();
    u16* sTb = simP + (size_t)khalf * 4194304 + (size_t)b * 512 * 512;
    {
        int n_l = t >> 1;
#pragma unroll
        for (int rep = 0; rep < 8; ++rep) {
            int c0 = (((t & 1) + rep * 2) << 3);
            s16x8 v = *(const s16x8*)&smem[n_l * 128 + (c0 ^ ((n_l & 15) << 3))];
            *(s16x8*)&sTb[(size_t)(n0 + n_l) * 512 + m0 + c0] = v;
        }
    }
}

// ================================================================ FINISH (single-pass, e[] in regs)
__global__ __launch_bounds__(256) void finish_kernel(const u16* __restrict__ p0,
                                                     const u16* __restrict__ p1,
                                                     const float* __restrict__ rm,
                                                     u16* __restrict__ attnT) {
    __shared__ float rml[32 * 513];   // rm rows c0..c0+31, stride 513 (conflict-free)
    __shared__ float scr[256];
    const int t = threadIdx.x;
    const int b = blockIdx.x >> 4, c0 = (blockIdx.x & 15) * 32;
    const int cl = t & 31, g = t >> 5;
    const float scale = 0.04419417382415922f;   // 512^-0.5

    for (int idx = t; idx < 32 * 512; idx += 256) {
        int c_l = idx >> 9, d = idx & 511;
        rml[c_l * 513 + d] = rm[(size_t)(c0 + c_l) * 512 + d];
    }
    __syncthreads();

    const u16* q0 = p0 + (size_t)b * 262144 + c0 + cl;
    const u16* q1 = p1 + (size_t)b * 262144 + c0 + cl;
    u16* ap = attnT + (size_t)b * 262144 + c0 + cl;
    const float* rp = &rml[cl * 513];

    float e[64];
    float s = 0.f;
#pragma unroll
    for (int dd = 0; dd < 64; ++dd) {
        int d = g * 64 + dd;
        float v = (bf2f(q0[(size_t)d * 512]) + bf2f(q1[(size_t)d * 512])) * scale + rp[d];
        e[dd] = __expf(v);
        s += e[dd];
    }
    scr[t] = s;
    __syncthreads();
    float tot = 0.f;
#pragma unroll
    for (int k = 0; k < 8; ++k) tot += scr[k * 32 + cl];
    float inv = 1.f / tot;
#pragma unroll
    for (int dd = 0; dd < 64; ++dd) {
        int d = g * 64 + dd;
        ap[(size_t)d * 512] = f2bf(e[dd] * inv);
    }
}

// ================================================================ conv implicit GEMM, split-K x2
// vTh[b][n][co] partial over K-half kh (36 of 72 kt steps each).
// grid (8,4,32): x = n-tile, y = co-tile, z>>1 = b, z&1 = kh.  1024 blocks (4/CU):
// co-resident blocks share wA/xT (no L2 thrash — R3 lesson) and fill each
// other's vmcnt(0)-drain stalls (m114 wave-level MFMA overlap).
__global__ __launch_bounds__(256) void conv_split(const u16* __restrict__ wA,
                                                  const u16* __restrict__ xT,
                                                  u16* __restrict__ vT0,
                                                  u16* __restrict__ vT1) {
    __shared__ __attribute__((aligned(16))) u16 smem[128 * 128];
    u16* As = smem;
    u16* Bs = smem + 128 * 64;
    const int b = blockIdx.z >> 1, kh = blockIdx.z & 1;
    const int m0 = blockIdx.y * 128, n0 = blockIdx.x * 128;
    const int t = threadIdx.x, w = t >> 6, l = t & 63;
    const u16* xTb = xT + (size_t)b * 1156 * 512;
    u16* vTd = (kh ? vT1 : vT0);

    int gi[4], pb[4];
    const u16* agp[4];
    u16 *ald[4], *bld[4];
#pragma unroll
    for (int i = 0; i < 4; ++i) {
        int rr = w * 8 + i * 32 + (l >> 3);
        gi[i] = (l & 7) ^ (rr & 7);
        agp[i] = wA + (size_t)(m0 + rr) * 4608 + gi[i] * 8;
        int n = n0 + rr;
        pb[i] = (n >> 5) * 34 + (n & 31);
        ald[i] = &As[(w * 8 + i * 32) * 64];
        bld[i] = &Bs[(w * 8 + i * 32) * 64];
    }

    f32x4 acc[4][4] = {};
    const int wm = (w >> 1) * 64, wn = (w & 1) * 64;

    for (int s = 0; s < 36; ++s) {
        int kt = kh * 36 + s;
        int r = kt >> 3, ci0k = (kt & 7) << 6;
        int rdiv3 = (r * 11) >> 5;
        int poff = rdiv3 * 34 + (r - rdiv3 * 3);
        int aofs = r * 512 + ci0k;
        if (s) __syncthreads();
#pragma unroll
        for (int i = 0; i < 4; ++i) gload_lds16(agp[i] + aofs, ald[i]);
#pragma unroll
        for (int i = 0; i < 4; ++i)
            gload_lds16(xTb + (size_t)(pb[i] + poff) * 512 + ci0k + gi[i] * 8, bld[i]);
        __syncthreads();

#pragma unroll
        for (int kk = 0; kk < 2; ++kk) {
            int gbase = kk * 4 + (l >> 4);
            s16x8 af[4], bf[4];
#pragma unroll
            for (int i = 0; i < 4; ++i) {
                int row = wm + i * 16 + (l & 15);
                af[i] = *(const s16x8*)&As[row * 64 + ((gbase ^ (row & 7)) << 3)];
            }
#pragma unroll
            for (int j = 0; j < 4; ++j) {
                int row = wn + j * 16 + (l & 15);
                bf[j] = *(const s16x8*)&Bs[row * 64 + ((gbase ^ (row & 7)) << 3)];
            }
#pragma unroll
            for (int i = 0; i < 4; ++i)
#pragma unroll
                for (int j = 0; j < 4; ++j)
                    acc[i][j] = __builtin_amdgcn_mfma_f32_16x16x32_bf16(af[i], bf[j], acc[i][j], 0, 0, 0);
        }
    }

    __syncthreads();
    const int col = l & 15, r4 = (l >> 4) * 4;
#pragma unroll
    for (int i = 0; i < 4; ++i)
#pragma unroll
        for (int j = 0; j < 4; ++j) {
            int n_l = wn + j * 16 + col;
            int co_b = wm + i * 16 + r4;
            u16x4 pk = {f2bf(acc[i][j][0]), f2bf(acc[i][j][1]),
                        f2bf(acc[i][j][2]), f2bf(acc[i][j][3])};
            *(u16x4*)&smem[n_l * 128 + (co_b ^ ((n_l & 15) << 3))] = pk;
        }
    __syncthreads();
    u16* vTb = vTd + (size_t)b * 1024 * 512;
    {
        int n_l = t >> 1;
#pragma unroll
        for (int rep = 0; rep < 8; ++rep) {
            int c0 = (((t & 1) + rep * 2) << 3);
            s16x8 v = *(const s16x8*)&smem[n_l * 128 + (c0 ^ ((n_l & 15) << 3))];
            *(s16x8*)&vTb[(size_t)(n0 + n_l) * 512 + m0 + c0] = v;
        }
    }
}

// ---- fallback full-K conv (only if ws too small for vT1; proven R2 path) ----
__global__ __launch_bounds__(256) void conv_gemm(const u16* __restrict__ wA,
                                                 const u16* __restrict__ xT,
                                                 u16* __restrict__ vT) {
    __shared__ __attribute__((aligned(16))) u16 smem[128 * 128];
    u16* As = smem;
    u16* Bs = smem + 128 * 64;
    const int b = blockIdx.z, m0 = blockIdx.y * 128, n0 = blockIdx.x * 128;
    const int t = threadIdx.x, w = t >> 6, l = t & 63;
    const u16* xTb = xT + (size_t)b * 1156 * 512;

    int gi[4], pb[4];
    const u16* agp[4];
    u16 *ald[4], *bld[4];
#pragma unroll
    for (int i = 0; i < 4; ++i) {
        int rr = w * 8 + i * 32 + (l >> 3);
        gi[i] = (l & 7) ^ (rr & 7);
        agp[i] = wA + (size_t)(m0 + rr) * 4608 + gi[i] * 8;
        int n = n0 + rr;
        pb[i] = (n >> 5) * 34 + (n & 31);
        ald[i] = &As[(w * 8 + i * 32) * 64];
        bld[i] = &Bs[(w * 8 + i * 32) * 64];
    }

    f32x4 acc[4][4] = {};
    const int wm = (w >> 1) * 64, wn = (w & 1) * 64;

    for (int kt = 0; kt < 72; ++kt) {
        int r = kt >> 3, ci0k = (kt & 7) << 6;
        int rdiv3 = (r * 11) >> 5;
        int poff = rdiv3 * 34 + (r - rdiv3 * 3);
        int aofs = r * 512 + ci0k;
        if (kt) __syncthreads();
#pragma unroll
        for (int i = 0; i < 4; ++i) gload_lds16(agp[i] + aofs, ald[i]);
#pragma unroll
        for (int i = 0; i < 4; ++i)
            gload_lds16(xTb + (size_t)(pb[i] + poff) * 512 + ci0k + gi[i] * 8, bld[i]);
        __syncthreads();

#pragma unroll
        for (int kk = 0; kk < 2; ++kk) {
            int gbase = kk * 4 + (l >> 4);
            s16x8 af[4], bf[4];
#pragma unroll
            for (int i = 0; i < 4; ++i) {
                int row = wm + i * 16 + (l & 15);
                af[i] = *(const s16x8*)&As[row * 64 + ((gbase ^ (row & 7)) << 3)];
            }
#pragma unroll
            for (int j = 0; j < 4; ++j) {
                int row = wn + j * 16 + (l & 15);
                bf[j] = *(const s16x8*)&Bs[row * 64 + ((gbase ^ (row & 7)) << 3)];
            }
#pragma unroll
            for (int i = 0; i < 4; ++i)
#pragma unroll
                for (int j = 0; j < 4; ++j)
                    acc[i][j] = __builtin_amdgcn_mfma_f32_16x16x32_bf16(af[i], bf[j], acc[i][j], 0, 0, 0);
        }
    }

    __syncthreads();
    const int col = l & 15, r4 = (l >> 4) * 4;
#pragma unroll
    for (int i = 0; i < 4; ++i)
#pragma unroll
        for (int j = 0; j < 4; ++j) {
            int n_l = wn + j * 16 + col;
            int co_b = wm + i * 16 + r4;
            u16x4 pk = {f2bf(acc[i][j][0]), f2bf(acc[i][j][1]),
                        f2bf(acc[i][j][2]), f2bf(acc[i][j][3])};
            *(u16x4*)&smem[n_l * 128 + (co_b ^ ((n_l & 15) << 3))] = pk;
        }
    __syncthreads();
    u16* vTb = vT + (size_t)b * 1024 * 512;
    {
        int n_l = t >> 1;
#pragma unroll
        for (int rep = 0; rep < 8; ++rep) {
            int c0 = (((t & 1) + rep * 2) << 3);
            s16x8 v = *(const s16x8*)&smem[n_l * 128 + (c0 ^ ((n_l & 15) << 3))];
            *(s16x8*)&vTb[(size_t)(n0 + n_l) * 512 + m0 + c0] = v;
        }
    }
}

// ================================================================ generic bf16 MFMA NT GEMM (proven)
// MODE 1: bf16 out (wattn); MODE 2: f32 out (final, fallback)
template <int MODE>
__global__ __launch_bounds__(256) void gemm_nt(const u16* __restrict__ A, size_t sA,
                                               const u16* __restrict__ B, size_t sB,
                                               void* __restrict__ Cv, size_t sC,
                                               int K, int ldc) {
    __shared__ __attribute__((aligned(16))) u16 As[128 * 64];
    __shared__ __attribute__((aligned(16))) u16 Bs[128 * 64];
    const int b = blockIdx.z, m0 = blockIdx.y * 128, n0 = blockIdx.x * 128;
    const int t = threadIdx.x, w = t >> 6, l = t & 63;
    const u16* Ab = A + (size_t)b * sA;
    const u16* Bb = B + (size_t)b * sB;

    const u16 *agp[4], *bgp[4];
    u16 *ald[4], *bld[4];
#pragma unroll
    for (int i = 0; i < 4; ++i) {
        int rr = w * 8 + i * 32 + (l >> 3);
        int gi = (l & 7) ^ (rr & 7);
        agp[i] = Ab + (size_t)(m0 + rr) * K + gi * 8;
        bgp[i] = Bb + (size_t)(n0 + rr) * K + gi * 8;
        ald[i] = &As[(w * 8 + i * 32) * 64];
        bld[i] = &Bs[(w * 8 + i * 32) * 64];
    }

    f32x4 acc[4][4] = {};
    const int wm = (w >> 1) * 64, wn = (w & 1) * 64;
    const int nkt = K >> 6;
    for (int kt = 0; kt < nkt; ++kt) {
        int ko = kt << 6;
        if (kt) __syncthreads();
#pragma unroll
        for (int i = 0; i < 4; ++i) gload_lds16(agp[i] + ko, ald[i]);
#pragma unroll
        for (int i = 0; i < 4; ++i) gload_lds16(bgp[i] + ko, bld[i]);
        __syncthreads();
#pragma unroll
        for (int kk = 0; kk < 2; ++kk) {
            int gbase = kk * 4 + (l >> 4);
            s16x8 af[4], bf[4];
#pragma unroll
            for (int i = 0; i < 4; ++i) {
                int row = wm + i * 16 + (l & 15);
                af[i] = *(const s16x8*)&As[row * 64 + ((gbase ^ (row & 7)) << 3)];
            }
#pragma unroll
            for (int j = 0; j < 4; ++j) {
                int row = wn + j * 16 + (l & 15);
                bf[j] = *(const s16x8*)&Bs[row * 64 + ((gbase ^ (row & 7)) << 3)];
            }
#pragma unroll
            for (int i = 0; i < 4; ++i)
#pragma unroll
                for (int j = 0; j < 4; ++j)
                    acc[i][j] = __builtin_amdgcn_mfma_f32_16x16x32_bf16(af[i], bf[j], acc[i][j], 0, 0, 0);
        }
    }

    const int col = l & 15, r4 = (l >> 4) * 4;
#pragma unroll
    for (int i = 0; i < 4; ++i)
#pragma unroll
        for (int j = 0; j < 4; ++j)
#pragma unroll
            for (int reg = 0; reg < 4; ++reg) {
                int m = m0 + wm + i * 16 + r4 + reg;
                int n = n0 + wn + j * 16 + col;
                if (MODE == 1) {
                    u16* C = (u16*)Cv + (size_t)b * sC;
                    C[(size_t)m * ldc + n] = f2bf(acc[i][j][reg]);
                } else {
                    float* C = (float*)Cv + (size_t)b * sC;
                    C[(size_t)m * ldc + n] = acc[i][j][reg];
                }
            }
}

// ================================================================ final GEMM, dual-B (split-K conv)
// out[b][o][n] = sum_d wattn[b][o][d] * (vT0[b][n][d] + vT1[b][n][d])
// == K=1024 contraction over [vT0|vT1] with the wattn A-panel applied twice.
__global__ __launch_bounds__(256) void gemm_final2(const u16* __restrict__ A,
                                                   const u16* __restrict__ B0,
                                                   const u16* __restrict__ B1,
                                                   float* __restrict__ C) {
    __shared__ __attribute__((aligned(16))) u16 As[128 * 64];
    __shared__ __attribute__((aligned(16))) u16 Bs[128 * 64];
    const int b = blockIdx.z, m0 = blockIdx.y * 128, n0 = blockIdx.x * 128;
    const int t = threadIdx.x, w = t >> 6, l = t & 63;
    const u16* Ab = A + (size_t)b * 256 * 512;
    const u16* B0b = B0 + (size_t)b * 1024 * 512;
    const u16* B1b = B1 + (size_t)b * 1024 * 512;

    const u16* agp[4];
    size_t boff[4];
    u16 *ald[4], *bld[4];
#pragma unroll
    for (int i = 0; i < 4; ++i) {
        int rr = w * 8 + i * 32 + (l >> 3);
        int gi = (l & 7) ^ (rr & 7);
        agp[i] = Ab + (size_t)(m0 + rr) * 512 + gi * 8;
        boff[i] = (size_t)(n0 + rr) * 512 + gi * 8;
        ald[i] = &As[(w * 8 + i * 32) * 64];
        bld[i] = &Bs[(w * 8 + i * 32) * 64];
    }

    f32x4 acc[4][4] = {};
    const int wm = (w >> 1) * 64, wn = (w & 1) * 64;
    for (int kt = 0; kt < 16; ++kt) {
        int ko = (kt & 7) << 6;                     // A wraps: same wattn panel both halves
        const u16* Bb = (kt < 8) ? B0b : B1b;
        if (kt) __syncthreads();
#pragma unroll
        for (int i = 0; i < 4; ++i) gload_lds16(agp[i] + ko, ald[i]);
#pragma unroll
        for (int i = 0; i < 4; ++i) gload_lds16(Bb + boff[i] + ko, bld[i]);
        __syncthreads();
#pragma unroll
        for (int kk = 0; kk < 2; ++kk) {
            int gbase = kk * 4 + (l >> 4);
            s16x8 af[4], bf[4];
#pragma unroll
            for (int i = 0; i < 4; ++i) {
                int row = wm + i * 16 + (l & 15);
                af[i] = *(const s16x8*)&As[row * 64 + ((gbase ^ (row & 7)) << 3)];
            }
#pragma unroll
            for (int j = 0; j < 4; ++j) {
                int row = wn + j * 16 + (l & 15);
                bf[j] = *(const s16x8*)&Bs[row * 64 + ((gbase ^ (row & 7)) << 3)];
            }
#pragma unroll
            for (int i = 0; i < 4; ++i)
#pragma unroll
                for (int j = 0; j < 4; ++j)
                    acc[i][j] = __builtin_amdgcn_mfma_f32_16x16x32_bf16(af[i], bf[j], acc[i][j], 0, 0, 0);
        }
    }

    const int col = l & 15, r4 = (l >> 4) * 4;
    float* Cb = C + (size_t)b * 256 * 1024;
#pragma unroll
    for (int i = 0; i < 4; ++i)
#pragma unroll
        for (int j = 0; j < 4; ++j)
#pragma unroll
            for (int reg = 0; reg < 4; ++reg) {
                int m = m0 + wm + i * 16 + r4 + reg;
                int n = n0 + wn + j * 16 + col;
                Cb[(size_t)m * 1024 + n] = acc[i][j][reg];
            }
}

// ----------------------------------------------------------------
extern "C" void kernel_launch(void* const* d_in, const int* in_sizes, int n_in,
                              void* d_out, int out_size, void* d_ws, size_t ws_size,
                              hipStream_t stream) {
    (void)in_sizes; (void)n_in; (void)out_size;
    const float* x1 = (const float*)d_in[0];
    const float* x2 = (const float*)d_in[1];
    const float* gw = (const float*)d_in[2];
    const float* ww = (const float*)d_in[3];
    const float* w1 = (const float*)d_in[4];
    const float* w2 = (const float*)d_in[5];
    float* out = (float*)d_out;
    float* ws = (float*)d_ws;

    u16* xT    = (u16*)(ws + OFF_XT);
    u16* xq    = (u16*)(ws + OFF_XQ);
    u16* attnT = (u16*)(ws + OFF_ATTNT);   // after xq dies
    u16* wattn = (u16*)(ws + OFF_WATTN);
    u16* simP  = (u16*)(ws + OFF_P0);      // p0; p1 at +4,194,304 u16
    u16* p0    = (u16*)(ws + OFF_P0);
    u16* p1    = (u16*)(ws + OFF_P1);
    u16* vT0   = (u16*)(ws + OFF_VT);      // after p0/p1 die
    u16* vT1   = (u16*)(ws + OFF_VT2);     // split-K partial (roomy ws, R3-proven)
    u16* wA    = (u16*)(ws + OFF_WA);
    float* rm  = ws + OFF_RM;
    u16* wwb   = (u16*)(ws + OFF_WWB);

    const bool splitk = ws_size >= (size_t)75300864;   // room for vT1 (held true in R3)

    prep_kernel<<<3728, 256, 0, stream>>>(x1, x2, gw, ww, w1, w2, rm, wA, wwb, xT, xq);
    // p{0,1}[b][d][c] = partial QQ^T halves (512 blocks, 2/CU)
    sim_part<<<dim3(8, 4, 16), 256, 0, stream>>>(xq, simP);
    // attnT[b][d][c] = softmax over d of ((p0+p1)*scale + rm[c][d])
    finish_kernel<<<256, 256, 0, stream>>>(p0, p1, rm, attnT);
    // wattn[b][o][d] = sum_c wwb[o][c] * attnT[b][d][c]  (bf16 out)
    gemm_nt<1><<<dim3(4, 2, 16), 256, 0, stream>>>(
        wwb, 0, attnT, (size_t)512 * 512, wattn, (size_t)256 * 512, 512, 512);

    if (splitk) {
        // conv split-K x2: 1024 blocks (4/CU), bf16 partials vT0/vT1
        conv_split<<<dim3(8, 4, 32), 256, 0, stream>>>(wA, xT, vT0, vT1);
        // out = wattn @ (vT0 + vT1)^T  via K=1024 dual-B contraction
        gemm_final2<<<dim3(8, 2, 16), 256, 0, stream>>>(wattn, vT0, vT1, out);
    } else {
        conv_gemm<<<dim3(8, 4, 16), 256, 0, stream>>>(wA, xT, vT0);
        gemm_nt<2><<<dim3(8, 2, 16), 256, 0, stream>>>(
            wattn, (size_t)256 * 512, vT0, (size_t)1024 * 512, out, (size_t)256 * 1024, 512, 1024);
    }
}

// Round 5
// 227.284 us; speedup vs baseline: 1.2110x; 1.0510x over previous
//
#include <hip/hip_runtime.h>
#include <math.h>

typedef float f32x4 __attribute__((ext_vector_type(4)));
typedef short s16x8 __attribute__((ext_vector_type(8)));
typedef unsigned int u32;
typedef unsigned short u16;
typedef u16 u16x4 __attribute__((ext_vector_type(4)));

// ---------------- ws layout (float offsets), 58.5 MB peak (== R2 proven) ----
static constexpr size_t OFF_XT    = 0;          // bf16 [16,1156,512]
static constexpr size_t OFF_XQ    = 4734976;
static constexpr size_t OFF_ATTNT = 4734976;    // after xq dies
static constexpr size_t OFF_WATTN = 6832128;
static constexpr size_t OFF_P0    = 8929280;    // bf16 [16,512,512]
static constexpr size_t OFF_P1    = 11026432;   // bf16 [16,512,512]
static constexpr size_t OFF_VT    = 8929280;    // after p0/p1 die
static constexpr size_t OFF_WA    = 13123584;   // bf16 [512,4608]
static constexpr size_t OFF_RM    = 14303232;   // f32 [512,512]
static constexpr size_t OFF_WWB   = 14565376;   // bf16 [256,512]
// end 14,630,912 fl = 58.5 MB

__device__ __forceinline__ u16 f2bf(float f) {
    u32 u = __float_as_uint(f);
    u32 r = (u + 0x7FFFu + ((u >> 16) & 1u)) >> 16;   // RNE
    return (u16)r;
}
__device__ __forceinline__ float bf2f(u16 v) {
    return __uint_as_float(((u32)v) << 16);
}

__device__ __forceinline__ void gload_lds16(const void* g, void* l) {
    __builtin_amdgcn_global_load_lds(
        (const u32 __attribute__((address_space(1)))*)(uintptr_t)g,
        (u32 __attribute__((address_space(3)))*)(uintptr_t)l, 16, 0, 0);
}

// ================================================================ PREP (R6/R8-proven)
__global__ __launch_bounds__(256) void prep_kernel(const float* __restrict__ x1,
                                                   const float* __restrict__ x2,
                                                   const float* __restrict__ gw,
                                                   const float* __restrict__ ww,
                                                   const float* __restrict__ w1,
                                                   const float* __restrict__ w2,
                                                   float* __restrict__ rm,
                                                   u16* __restrict__ wA,
                                                   u16* __restrict__ wwb,
                                                   u16* __restrict__ xT,
                                                   u16* __restrict__ xq) {
    __shared__ __attribute__((aligned(16))) u32 shm[4608];
    const int t = threadIdx.x;
    const int bid = blockIdx.x;

    if (bid < 512) {                        // ---- gw permute-cast
        const int co = bid;
        const float* g = gw + (size_t)co * 4608;
        float* lf = (float*)shm;
#pragma unroll
        for (int i = 0; i < 18; ++i) lf[t + i * 256] = g[t + i * 256];
        __syncthreads();
        u16* dst = wA + (size_t)co * 4608;
#pragma unroll
        for (int i = 0; i < 18; ++i) {
            int k = t + i * 256;
            int r = k >> 9, ci = k & 511;
            dst[k] = f2bf(lf[ci * 9 + r]);
        }
    } else if (bid < 2560) {                // ---- x fused cast + transpose
        int xid = bid - 512;
        int nt = xid & 15;
        int cit = (xid >> 4) & 7;
        int b = xid >> 7;
        int n0 = nt * 64, ci0 = cit * 64;
        const float* src = (ci0 < 256) ? (x1 + ((size_t)(b * 256 + ci0)) * 1024)
                                       : (x2 + ((size_t)(b * 256 + ci0 - 256)) * 1024);
        u16* xqb = xq + ((size_t)(b * 512 + ci0)) * 1024;
        u16* lt = (u16*)shm;
#pragma unroll
        for (int p4 = 0; p4 < 4; ++p4) {
            int ch = (t >> 4) + p4 * 16;
            int px = (t & 15) * 4;
            float4 v = *(const float4*)&src[(size_t)ch * 1024 + n0 + px];
            u16x4 pk = {f2bf(v.x), f2bf(v.y), f2bf(v.z), f2bf(v.w)};
            *(u16x4*)&xqb[(size_t)ch * 1024 + n0 + px] = pk;
            lt[(px + 0) * 65 + ch] = pk[0];
            lt[(px + 1) * 65 + ch] = pk[1];
            lt[(px + 2) * 65 + ch] = pk[2];
            lt[(px + 3) * 65 + ch] = pk[3];
        }
        __syncthreads();
        {
            int px_l = t >> 2, c16 = (t & 3) * 16;
            int n = n0 + px_l;
            int y = n >> 5, x = n & 31;
            int p = (y + 1) * 34 + (x + 1);
            u16* dst = xT + ((size_t)b * 1156 + p) * 512 + ci0 + c16;
            *(s16x8*)&dst[0] = *(const s16x8*)&lt[px_l * 65 + c16];
            *(s16x8*)&dst[8] = *(const s16x8*)&lt[px_l * 65 + c16 + 8];
        }
    } else if (bid < 2576) {                // ---- border zero
        int b = bid - 2560;
        u16* base = xT + (size_t)b * 1156 * 512;
        s16x8 z = {0, 0, 0, 0, 0, 0, 0, 0};
        for (int idx = t; idx < 132 * 64; idx += 256) {
            int row = idx >> 6, seg = idx & 63;
            int p;
            if (row < 34) p = row;
            else if (row < 68) p = 1122 + (row - 34);
            else if (row < 100) p = (row - 67) * 34;
            else p = (row - 99) * 34 + 33;
            *(s16x8*)&base[(size_t)p * 512 + seg * 8] = z;
        }
    } else if (bid < 3600) {                // ---- rm
        int idx = (bid - 2576) * 256 + t;
        int c = idx >> 9, d = idx & 511;
        float s = 0.f;
#pragma unroll
        for (int k = 0; k < 16; ++k) s = fmaf(w1[c * 16 + k], w2[d * 16 + k], s);
        rm[idx] = s;
    } else {                                // ---- wwb cast
        int idx = (bid - 3600) * 256 + t;
        float4 v = ((const float4*)ww)[idx];
        u16x4 pk = {f2bf(v.x), f2bf(v.y), f2bf(v.z), f2bf(v.w)};
        *(u16x4*)&wwb[(size_t)idx * 4] = pk;
    }
}

// ================================================================ SIM partial GEMM (proven)
__global__ __launch_bounds__(256) void sim_part(const u16* __restrict__ xq,
                                                u16* __restrict__ simP) {
    __shared__ __attribute__((aligned(16))) u16 smem[128 * 128];
    u16* As = smem;
    u16* Bs = smem + 128 * 64;
    const int b = blockIdx.z, m0 = blockIdx.y * 128;
    const int n0 = (blockIdx.x & 3) * 128, khalf = blockIdx.x >> 2;
    const int t = threadIdx.x, w = t >> 6, l = t & 63;
    const u16* xb = xq + (size_t)b * 512 * 1024 + khalf * 512;

    const u16 *agp[4], *bgp[4];
    u16 *ald[4], *bld[4];
#pragma unroll
    for (int i = 0; i < 4; ++i) {
        int rr = w * 8 + i * 32 + (l >> 3);
        int gi = (l & 7) ^ (rr & 7);
        agp[i] = xb + (size_t)(m0 + rr) * 1024 + gi * 8;
        bgp[i] = xb + (size_t)(n0 + rr) * 1024 + gi * 8;
        ald[i] = &As[(w * 8 + i * 32) * 64];
        bld[i] = &Bs[(w * 8 + i * 32) * 64];
    }

    f32x4 acc[4][4] = {};
    const int wm = (w >> 1) * 64, wn = (w & 1) * 64;

    for (int kt = 0; kt < 8; ++kt) {
        int ko = kt << 6;
        if (kt) __syncthreads();
#pragma unroll
        for (int i = 0; i < 4; ++i) gload_lds16(agp[i] + ko, ald[i]);
#pragma unroll
        for (int i = 0; i < 4; ++i) gload_lds16(bgp[i] + ko, bld[i]);
        __syncthreads();
#pragma unroll
        for (int kk = 0; kk < 2; ++kk) {
            int gbase = kk * 4 + (l >> 4);
            s16x8 af[4], bf[4];
#pragma unroll
            for (int i = 0; i < 4; ++i) {
                int row = wm + i * 16 + (l & 15);
                af[i] = *(const s16x8*)&As[row * 64 + ((gbase ^ (row & 7)) << 3)];
            }
#pragma unroll
            for (int j = 0; j < 4; ++j) {
                int row = wn + j * 16 + (l & 15);
                bf[j] = *(const s16x8*)&Bs[row * 64 + ((gbase ^ (row & 7)) << 3)];
            }
#pragma unroll
            for (int i = 0; i < 4; ++i)
#pragma unroll
                for (int j = 0; j < 4; ++j)
                    acc[i][j] = __builtin_amdgcn_mfma_f32_16x16x32_bf16(af[i], bf[j], acc[i][j], 0, 0, 0);
        }
    }

    __syncthreads();
    const int col = l & 15, r4 = (l >> 4) * 4;
#pragma unroll
    for (int i = 0; i < 4; ++i)
#pragma unroll
        for (int j = 0; j < 4; ++j) {
            int n_l = wn + j * 16 + col;
            int m_b = wm + i * 16 + r4;
            u16x4 pk = {f2bf(acc[i][j][0]), f2bf(acc[i][j][1]),
                        f2bf(acc[i][j][2]), f2bf(acc[i][j][3])};
            *(u16x4*)&smem[n_l * 128 + (m_b ^ ((n_l & 15) << 3))] = pk;
        }
    __syncthreads();
    u16* sTb = simP + (size_t)khalf * 4194304 + (size_t)b * 512 * 512;
    {
        int n_l = t >> 1;
#pragma unroll
        for (int rep = 0; rep < 8; ++rep) {
            int c0 = (((t & 1) + rep * 2) << 3);
            s16x8 v = *(const s16x8*)&smem[n_l * 128 + (c0 ^ ((n_l & 15) << 3))];
            *(s16x8*)&sTb[(size_t)(n0 + n_l) * 512 + m0 + c0] = v;
        }
    }
}

// ================================================================ FINISH (single-pass, proven R2)
__global__ __launch_bounds__(256) void finish_kernel(const u16* __restrict__ p0,
                                                     const u16* __restrict__ p1,
                                                     const float* __restrict__ rm,
                                                     u16* __restrict__ attnT) {
    __shared__ float rml[32 * 513];
    __shared__ float scr[256];
    const int t = threadIdx.x;
    const int b = blockIdx.x >> 4, c0 = (blockIdx.x & 15) * 32;
    const int cl = t & 31, g = t >> 5;
    const float scale = 0.04419417382415922f;   // 512^-0.5

    for (int idx = t; idx < 32 * 512; idx += 256) {
        int c_l = idx >> 9, d = idx & 511;
        rml[c_l * 513 + d] = rm[(size_t)(c0 + c_l) * 512 + d];
    }
    __syncthreads();

    const u16* q0 = p0 + (size_t)b * 262144 + c0 + cl;
    const u16* q1 = p1 + (size_t)b * 262144 + c0 + cl;
    u16* ap = attnT + (size_t)b * 262144 + c0 + cl;
    const float* rp = &rml[cl * 513];

    float e[64];
    float s = 0.f;
#pragma unroll
    for (int dd = 0; dd < 64; ++dd) {
        int d = g * 64 + dd;
        float v = (bf2f(q0[(size_t)d * 512]) + bf2f(q1[(size_t)d * 512])) * scale + rp[d];
        e[dd] = __expf(v);
        s += e[dd];
    }
    scr[t] = s;
    __syncthreads();
    float tot = 0.f;
#pragma unroll
    for (int k = 0; k < 8; ++k) tot += scr[k * 32 + cl];
    float inv = 1.f / tot;
#pragma unroll
    for (int dd = 0; dd < 64; ++dd) {
        int d = g * 64 + dd;
        ap[(size_t)d * 512] = f2bf(e[dd] * inv);
    }
}

// ================================================================ CONV, 8-phase schedule (T2+T3+T4+T5)
// Implicit GEMM vT[b][n][co] = sum_k wA[co][k] xT[b][pix(n,r)][ci], K = 72 tiles of 64.
// BM=128 (co), BN=256 (n), BK=64. 512 thr = 8 waves (2M x 4N), per-wave 64x64 (4x4 frags).
// 3-deep LDS pipeline (144 KB): compute tile j from buf[j%3] while tile j+2 stages into
// buf[(j+2)%3]; boundary wait = s_waitcnt vmcnt(6) (tile j+1's 6 loads stay in flight) —
// never drained in the main loop (T4). Per tile: 2 phases x {ds_read; 3 stage-issues;
// s_barrier; setprio(1); 16 MFMA; setprio(0); s_barrier}  == 8 phases / 2 K-tiles (T3).
__global__ __launch_bounds__(512) void conv_8ph(const u16* __restrict__ wA,
                                                const u16* __restrict__ xT,
                                                u16* __restrict__ vT) {
    __shared__ __attribute__((aligned(16))) u16 smem[73728];   // 3 x (A 8192 + B 16384) u16
    const int b = blockIdx.z, m0 = blockIdx.y * 128, n0 = blockIdx.x * 256;
    const int t = threadIdx.x, w = t >> 6, l = t & 63;
    const u16* xTb = xT + (size_t)b * 1156 * 512;

    // ---- staging addressing (per-thread, XOR-preswizzled source; LDS dest linear)
    const u16* agp[2];
    int pbb[4], giB[4];
#pragma unroll
    for (int i = 0; i < 2; ++i) {
        int rr = i * 64 + w * 8 + (l >> 3);
        int gi = (l & 7) ^ (rr & 7);
        agp[i] = wA + (size_t)(m0 + rr) * 4608 + gi * 8;
    }
#pragma unroll
    for (int i = 0; i < 4; ++i) {
        int rr = i * 64 + w * 8 + (l >> 3);
        int n = n0 + rr;
        pbb[i] = (n >> 5) * 34 + (n & 31);
        giB[i] = (l & 7) ^ (rr & 7);
    }

    // stage one full K-tile (6 gload_lds/thread: A0 A1 B0 B1 B2 B3)
    auto stage_tile = [&](int kt, u16* dA, u16* dB) {
        int r = kt >> 3, ci0 = (kt & 7) << 6;
        int rd3 = (r * 11) >> 5;
        int poff = rd3 * 34 + (r - rd3 * 3);
        int aofs = r * 512 + ci0;
        gload_lds16(agp[0] + aofs, dA + (w * 8) * 64);
        gload_lds16(agp[1] + aofs, dA + (64 + w * 8) * 64);
        gload_lds16(xTb + (size_t)(pbb[0] + poff) * 512 + ci0 + giB[0] * 8, dB + (w * 8) * 64);
        gload_lds16(xTb + (size_t)(pbb[1] + poff) * 512 + ci0 + giB[1] * 8, dB + (64 + w * 8) * 64);
        gload_lds16(xTb + (size_t)(pbb[2] + poff) * 512 + ci0 + giB[2] * 8, dB + (128 + w * 8) * 64);
        gload_lds16(xTb + (size_t)(pbb[3] + poff) * 512 + ci0 + giB[3] * 8, dB + (192 + w * 8) * 64);
    };

    // prologue: tiles 0 and 1 (12 loads in flight)
    stage_tile(0, smem, smem + 8192);
    stage_tile(1, smem + 24576, smem + 24576 + 8192);

    f32x4 acc[4][4] = {};
    const int wmo = (w >> 2) * 64, wno = (w & 3) * 64;
    const int lr = l & 15, gb0 = l >> 4;

    int cur = 0;
    for (int j = 0; j < 72; ++j) {
        int stg = cur + 2; if (stg >= 3) stg -= 3;
        u16* cA = smem + cur * 24576;
        u16* cB = cA + 8192;
        u16* sA = smem + stg * 24576;
        u16* sB = sA + 8192;
        const bool dost = (j + 2) < 72;
        int r2 = 0, ci02 = 0, poff2 = 0, aofs2 = 0;
        if (dost) {
            int kt2 = j + 2;
            r2 = kt2 >> 3; ci02 = (kt2 & 7) << 6;
            int rd3 = (r2 * 11) >> 5;
            poff2 = rd3 * 34 + (r2 - rd3 * 3);
            aofs2 = r2 * 512 + ci02;
        }

        // ---- tile boundary: wait tile j's 6 loads (tile j+1's stay in flight)
        if (j < 71) asm volatile("s_waitcnt vmcnt(6)" ::: "memory");
        else        asm volatile("s_waitcnt vmcnt(0)" ::: "memory");
        __builtin_amdgcn_s_barrier();

        s16x8 af[4][2], bf[4][2];
        // ================= PHASE A: read A-frags + B nj{0,1}; stage A0,A1,B0; MFMA nj{0,1}
#pragma unroll
        for (int mi = 0; mi < 4; ++mi) {
            int row = wmo + mi * 16 + lr;
#pragma unroll
            for (int ks = 0; ks < 2; ++ks)
                af[mi][ks] = *(const s16x8*)&cA[row * 64 + (((ks * 4 + gb0) ^ (row & 7)) << 3)];
        }
#pragma unroll
        for (int q = 0; q < 2; ++q) {
            int row = wno + q * 16 + lr;
#pragma unroll
            for (int ks = 0; ks < 2; ++ks)
                bf[q][ks] = *(const s16x8*)&cB[row * 64 + (((ks * 4 + gb0) ^ (row & 7)) << 3)];
        }
        if (dost) {
            gload_lds16(agp[0] + aofs2, sA + (w * 8) * 64);
            gload_lds16(agp[1] + aofs2, sA + (64 + w * 8) * 64);
            gload_lds16(xTb + (size_t)(pbb[0] + poff2) * 512 + ci02 + giB[0] * 8, sB + (w * 8) * 64);
        }
        __builtin_amdgcn_s_barrier();
        __builtin_amdgcn_s_setprio(1);
#pragma unroll
        for (int ks = 0; ks < 2; ++ks)
#pragma unroll
            for (int q = 0; q < 2; ++q)
#pragma unroll
                for (int mi = 0; mi < 4; ++mi)
                    acc[mi][q] = __builtin_amdgcn_mfma_f32_16x16x32_bf16(af[mi][ks], bf[q][ks], acc[mi][q], 0, 0, 0);
        __builtin_amdgcn_s_setprio(0);
        __builtin_amdgcn_s_barrier();

        // ================= PHASE B: read B nj{2,3}; stage B1,B2,B3; MFMA nj{2,3}
#pragma unroll
        for (int q = 2; q < 4; ++q) {
            int row = wno + q * 16 + lr;
#pragma unroll
            for (int ks = 0; ks < 2; ++ks)
                bf[q][ks] = *(const s16x8*)&cB[row * 64 + (((ks * 4 + gb0) ^ (row & 7)) << 3)];
        }
        if (dost) {
            gload_lds16(xTb + (size_t)(pbb[1] + poff2) * 512 + ci02 + giB[1] * 8, sB + (64 + w * 8) * 64);
            gload_lds16(xTb + (size_t)(pbb[2] + poff2) * 512 + ci02 + giB[2] * 8, sB + (128 + w * 8) * 64);
            gload_lds16(xTb + (size_t)(pbb[3] + poff2) * 512 + ci02 + giB[3] * 8, sB + (192 + w * 8) * 64);
        }
        __builtin_amdgcn_s_barrier();
        __builtin_amdgcn_s_setprio(1);
#pragma unroll
        for (int ks = 0; ks < 2; ++ks)
#pragma unroll
            for (int q = 2; q < 4; ++q)
#pragma unroll
                for (int mi = 0; mi < 4; ++mi)
                    acc[mi][q] = __builtin_amdgcn_mfma_f32_16x16x32_bf16(af[mi][ks], bf[q][ks], acc[mi][q], 0, 0, 0);
        __builtin_amdgcn_s_setprio(0);
        __builtin_amdgcn_s_barrier();

        cur += 1; if (cur >= 3) cur -= 3;
    }

    // ---- epilogue: acc -> LDS (XOR-swizzled 256x128) -> coalesced vT store
    __syncthreads();
    const int col = l & 15, r4 = (l >> 4) * 4;
#pragma unroll
    for (int mi = 0; mi < 4; ++mi)
#pragma unroll
        for (int nj = 0; nj < 4; ++nj) {
            int n_l = wno + nj * 16 + col;
            int co_b = wmo + mi * 16 + r4;
            u16x4 pk = {f2bf(acc[mi][nj][0]), f2bf(acc[mi][nj][1]),
                        f2bf(acc[mi][nj][2]), f2bf(acc[mi][nj][3])};
            *(u16x4*)&smem[n_l * 128 + (co_b ^ ((n_l & 15) << 3))] = pk;
        }
    __syncthreads();
    u16* vTb = vT + (size_t)b * 1024 * 512;
    {
        int n_l = t >> 1;
#pragma unroll
        for (int rep = 0; rep < 8; ++rep) {
            int c0 = (((t & 1) + rep * 2) << 3);
            s16x8 v = *(const s16x8*)&smem[n_l * 128 + (c0 ^ ((n_l & 15) << 3))];
            *(s16x8*)&vTb[(size_t)(n0 + n_l) * 512 + m0 + c0] = v;
        }
    }
}

// ================================================================ generic bf16 MFMA NT GEMM (proven)
// MODE 1: bf16 out (wattn); MODE 2: f32 out (final)
template <int MODE>
__global__ __launch_bounds__(256) void gemm_nt(const u16* __restrict__ A, size_t sA,
                                               const u16* __restrict__ B, size_t sB,
                                               void* __restrict__ Cv, size_t sC,
                                               int K, int ldc) {
    __shared__ __attribute__((aligned(16))) u16 As[128 * 64];
    __shared__ __attribute__((aligned(16))) u16 Bs[128 * 64];
    const int b = blockIdx.z, m0 = blockIdx.y * 128, n0 = blockIdx.x * 128;
    const int t = threadIdx.x, w = t >> 6, l = t & 63;
    const u16* Ab = A + (size_t)b * sA;
    const u16* Bb = B + (size_t)b * sB;

    const u16 *agp[4], *bgp[4];
    u16 *ald[4], *bld[4];
#pragma unroll
    for (int i = 0; i < 4; ++i) {
        int rr = w * 8 + i * 32 + (l >> 3);
        int gi = (l & 7) ^ (rr & 7);
        agp[i] = Ab + (size_t)(m0 + rr) * K + gi * 8;
        bgp[i] = Bb + (size_t)(n0 + rr) * K + gi * 8;
        ald[i] = &As[(w * 8 + i * 32) * 64];
        bld[i] = &Bs[(w * 8 + i * 32) * 64];
    }

    f32x4 acc[4][4] = {};
    const int wm = (w >> 1) * 64, wn = (w & 1) * 64;
    const int nkt = K >> 6;
    for (int kt = 0; kt < nkt; ++kt) {
        int ko = kt << 6;
        if (kt) __syncthreads();
#pragma unroll
        for (int i = 0; i < 4; ++i) gload_lds16(agp[i] + ko, ald[i]);
#pragma unroll
        for (int i = 0; i < 4; ++i) gload_lds16(bgp[i] + ko, bld[i]);
        __syncthreads();
#pragma unroll
        for (int kk = 0; kk < 2; ++kk) {
            int gbase = kk * 4 + (l >> 4);
            s16x8 af[4], bf[4];
#pragma unroll
            for (int i = 0; i < 4; ++i) {
                int row = wm + i * 16 + (l & 15);
                af[i] = *(const s16x8*)&As[row * 64 + ((gbase ^ (row & 7)) << 3)];
            }
#pragma unroll
            for (int j = 0; j < 4; ++j) {
                int row = wn + j * 16 + (l & 15);
                bf[j] = *(const s16x8*)&Bs[row * 64 + ((gbase ^ (row & 7)) << 3)];
            }
#pragma unroll
            for (int i = 0; i < 4; ++i)
#pragma unroll
                for (int j = 0; j < 4; ++j)
                    acc[i][j] = __builtin_amdgcn_mfma_f32_16x16x32_bf16(af[i], bf[j], acc[i][j], 0, 0, 0);
        }
    }

    const int col = l & 15, r4 = (l >> 4) * 4;
#pragma unroll
    for (int i = 0; i < 4; ++i)
#pragma unroll
        for (int j = 0; j < 4; ++j)
#pragma unroll
            for (int reg = 0; reg < 4; ++reg) {
                int m = m0 + wm + i * 16 + r4 + reg;
                int n = n0 + wn + j * 16 + col;
                if (MODE == 1) {
                    u16* C = (u16*)Cv + (size_t)b * sC;
                    C[(size_t)m * ldc + n] = f2bf(acc[i][j][reg]);
                } else {
                    float* C = (float*)Cv + (size_t)b * sC;
                    C[(size_t)m * ldc + n] = acc[i][j][reg];
                }
            }
}

// ----------------------------------------------------------------
extern "C" void kernel_launch(void* const* d_in, const int* in_sizes, int n_in,
                              void* d_out, int out_size, void* d_ws, size_t ws_size,
                              hipStream_t stream) {
    (void)in_sizes; (void)n_in; (void)out_size; (void)ws_size;
    const float* x1 = (const float*)d_in[0];
    const float* x2 = (const float*)d_in[1];
    const float* gw = (const float*)d_in[2];
    const float* ww = (const float*)d_in[3];
    const float* w1 = (const float*)d_in[4];
    const float* w2 = (const float*)d_in[5];
    float* out = (float*)d_out;
    float* ws = (float*)d_ws;

    u16* xT    = (u16*)(ws + OFF_XT);
    u16* xq    = (u16*)(ws + OFF_XQ);
    u16* attnT = (u16*)(ws + OFF_ATTNT);   // after xq dies
    u16* wattn = (u16*)(ws + OFF_WATTN);
    u16* simP  = (u16*)(ws + OFF_P0);      // p0; p1 at +4,194,304 u16
    u16* p0    = (u16*)(ws + OFF_P0);
    u16* p1    = (u16*)(ws + OFF_P1);
    u16* vT    = (u16*)(ws + OFF_VT);      // after p0/p1 die
    u16* wA    = (u16*)(ws + OFF_WA);
    float* rm  = ws + OFF_RM;
    u16* wwb   = (u16*)(ws + OFF_WWB);

    prep_kernel<<<3728, 256, 0, stream>>>(x1, x2, gw, ww, w1, w2, rm, wA, wwb, xT, xq);
    // p{0,1}[b][d][c] = partial QQ^T halves (512 blocks, 2/CU)
    sim_part<<<dim3(8, 4, 16), 256, 0, stream>>>(xq, simP);
    // attnT[b][d][c] = softmax over d of ((p0+p1)*scale + rm[c][d])
    finish_kernel<<<256, 256, 0, stream>>>(p0, p1, rm, attnT);
    // wattn[b][o][d] = sum_c wwb[o][c] * attnT[b][d][c]  (bf16 out)
    gemm_nt<1><<<dim3(4, 2, 16), 256, 0, stream>>>(
        wwb, 0, attnT, (size_t)512 * 512, wattn, (size_t)256 * 512, 512, 512);
    // conv, 8-phase pipelined: 256 blocks (1/CU), 512 thr
    conv_8ph<<<dim3(4, 4, 16), 512, 0, stream>>>(wA, xT, vT);
    // out[b][o][n] = sum_d wattn[b][o][d] * vT[b][n][d]  (f32 out)
    gemm_nt<2><<<dim3(8, 2, 16), 256, 0, stream>>>(
        wattn, (size_t)256 * 512, vT, (size_t)1024 * 512, out, (size_t)256 * 1024, 512, 1024);
}

// Round 7
// 223.791 us; speedup vs baseline: 1.2299x; 1.0156x over previous
//
#include <hip/hip_runtime.h>
#include <math.h>

typedef float f32x4 __attribute__((ext_vector_type(4)));
typedef short s16x8 __attribute__((ext_vector_type(8)));
typedef unsigned int u32;
typedef unsigned short u16;
typedef u16 u16x4 __attribute__((ext_vector_type(4)));

// ---------------- ws layout (float offsets), 58.5 MB peak (== R2 proven) ----
static constexpr size_t OFF_XT    = 0;          // bf16 [16,1156,512]
static constexpr size_t OFF_XQ    = 4734976;
static constexpr size_t OFF_ATTNT = 4734976;    // after xq dies
static constexpr size_t OFF_WATTN = 6832128;
static constexpr size_t OFF_P0    = 8929280;    // bf16 [16,512,512]
static constexpr size_t OFF_P1    = 11026432;   // bf16 [16,512,512]
static constexpr size_t OFF_VT    = 8929280;    // after p0/p1 die
static constexpr size_t OFF_WA    = 13123584;   // bf16 [512,4608]
static constexpr size_t OFF_RM    = 14303232;   // f32 [512,512]
static constexpr size_t OFF_WWB   = 14565376;   // bf16 [256,512]
// end 14,630,912 fl = 58.5 MB

__device__ __forceinline__ u16 f2bf(float f) {
    u32 u = __float_as_uint(f);
    u32 r = (u + 0x7FFFu + ((u >> 16) & 1u)) >> 16;   // RNE
    return (u16)r;
}
__device__ __forceinline__ float bf2f(u16 v) {
    return __uint_as_float(((u32)v) << 16);
}

__device__ __forceinline__ void gload_lds16(const void* g, void* l) {
    __builtin_amdgcn_global_load_lds(
        (const u32 __attribute__((address_space(1)))*)(uintptr_t)g,
        (u32 __attribute__((address_space(3)))*)(uintptr_t)l, 16, 0, 0);
}

// ================================================================ PREP (R6/R8-proven)
__global__ __launch_bounds__(256) void prep_kernel(const float* __restrict__ x1,
                                                   const float* __restrict__ x2,
                                                   const float* __restrict__ gw,
                                                   const float* __restrict__ ww,
                                                   const float* __restrict__ w1,
                                                   const float* __restrict__ w2,
                                                   float* __restrict__ rm,
                                                   u16* __restrict__ wA,
                                                   u16* __restrict__ wwb,
                                                   u16* __restrict__ xT,
                                                   u16* __restrict__ xq) {
    __shared__ __attribute__((aligned(16))) u32 shm[4608];
    const int t = threadIdx.x;
    const int bid = blockIdx.x;

    if (bid < 512) {                        // ---- gw permute-cast
        const int co = bid;
        const float* g = gw + (size_t)co * 4608;
        float* lf = (float*)shm;
#pragma unroll
        for (int i = 0; i < 18; ++i) lf[t + i * 256] = g[t + i * 256];
        __syncthreads();
        u16* dst = wA + (size_t)co * 4608;
#pragma unroll
        for (int i = 0; i < 18; ++i) {
            int k = t + i * 256;
            int r = k >> 9, ci = k & 511;
            dst[k] = f2bf(lf[ci * 9 + r]);
        }
    } else if (bid < 2560) {                // ---- x fused cast + transpose
        int xid = bid - 512;
        int nt = xid & 15;
        int cit = (xid >> 4) & 7;
        int b = xid >> 7;
        int n0 = nt * 64, ci0 = cit * 64;
        const float* src = (ci0 < 256) ? (x1 + ((size_t)(b * 256 + ci0)) * 1024)
                                       : (x2 + ((size_t)(b * 256 + ci0 - 256)) * 1024);
        u16* xqb = xq + ((size_t)(b * 512 + ci0)) * 1024;
        u16* lt = (u16*)shm;
#pragma unroll
        for (int p4 = 0; p4 < 4; ++p4) {
            int ch = (t >> 4) + p4 * 16;
            int px = (t & 15) * 4;
            float4 v = *(const float4*)&src[(size_t)ch * 1024 + n0 + px];
            u16x4 pk = {f2bf(v.x), f2bf(v.y), f2bf(v.z), f2bf(v.w)};
            *(u16x4*)&xqb[(size_t)ch * 1024 + n0 + px] = pk;
            lt[(px + 0) * 65 + ch] = pk[0];
            lt[(px + 1) * 65 + ch] = pk[1];
            lt[(px + 2) * 65 + ch] = pk[2];
            lt[(px + 3) * 65 + ch] = pk[3];
        }
        __syncthreads();
        {
            int px_l = t >> 2, c16 = (t & 3) * 16;
            int n = n0 + px_l;
            int y = n >> 5, x = n & 31;
            int p = (y + 1) * 34 + (x + 1);
            u16* dst = xT + ((size_t)b * 1156 + p) * 512 + ci0 + c16;
            *(s16x8*)&dst[0] = *(const s16x8*)&lt[px_l * 65 + c16];
            *(s16x8*)&dst[8] = *(const s16x8*)&lt[px_l * 65 + c16 + 8];
        }
    } else if (bid < 2576) {                // ---- border zero
        int b = bid - 2560;
        u16* base = xT + (size_t)b * 1156 * 512;
        s16x8 z = {0, 0, 0, 0, 0, 0, 0, 0};
        for (int idx = t; idx < 132 * 64; idx += 256) {
            int row = idx >> 6, seg = idx & 63;
            int p;
            if (row < 34) p = row;
            else if (row < 68) p = 1122 + (row - 34);
            else if (row < 100) p = (row - 67) * 34;
            else p = (row - 99) * 34 + 33;
            *(s16x8*)&base[(size_t)p * 512 + seg * 8] = z;
        }
    } else if (bid < 3600) {                // ---- rm
        int idx = (bid - 2576) * 256 + t;
        int c = idx >> 9, d = idx & 511;
        float s = 0.f;
#pragma unroll
        for (int k = 0; k < 16; ++k) s = fmaf(w1[c * 16 + k], w2[d * 16 + k], s);
        rm[idx] = s;
    } else {                                // ---- wwb cast
        int idx = (bid - 3600) * 256 + t;
        float4 v = ((const float4*)ww)[idx];
        u16x4 pk = {f2bf(v.x), f2bf(v.y), f2bf(v.z), f2bf(v.w)};
        *(u16x4*)&wwb[(size_t)idx * 4] = pk;
    }
}

// ================================================================ SIM partial GEMM (proven)
__global__ __launch_bounds__(256) void sim_part(const u16* __restrict__ xq,
                                                u16* __restrict__ simP) {
    __shared__ __attribute__((aligned(16))) u16 smem[128 * 128];
    u16* As = smem;
    u16* Bs = smem + 128 * 64;
    const int b = blockIdx.z, m0 = blockIdx.y * 128;
    const int n0 = (blockIdx.x & 3) * 128, khalf = blockIdx.x >> 2;
    const int t = threadIdx.x, w = t >> 6, l = t & 63;
    const u16* xb = xq + (size_t)b * 512 * 1024 + khalf * 512;

    const u16 *agp[4], *bgp[4];
    u16 *ald[4], *bld[4];
#pragma unroll
    for (int i = 0; i < 4; ++i) {
        int rr = w * 8 + i * 32 + (l >> 3);
        int gi = (l & 7) ^ (rr & 7);
        agp[i] = xb + (size_t)(m0 + rr) * 1024 + gi * 8;
        bgp[i] = xb + (size_t)(n0 + rr) * 1024 + gi * 8;
        ald[i] = &As[(w * 8 + i * 32) * 64];
        bld[i] = &Bs[(w * 8 + i * 32) * 64];
    }

    f32x4 acc[4][4] = {};
    const int wm = (w >> 1) * 64, wn = (w & 1) * 64;

    for (int kt = 0; kt < 8; ++kt) {
        int ko = kt << 6;
        if (kt) __syncthreads();
#pragma unroll
        for (int i = 0; i < 4; ++i) gload_lds16(agp[i] + ko, ald[i]);
#pragma unroll
        for (int i = 0; i < 4; ++i) gload_lds16(bgp[i] + ko, bld[i]);
        __syncthreads();
#pragma unroll
        for (int kk = 0; kk < 2; ++kk) {
            int gbase = kk * 4 + (l >> 4);
            s16x8 af[4], bf[4];
#pragma unroll
            for (int i = 0; i < 4; ++i) {
                int row = wm + i * 16 + (l & 15);
                af[i] = *(const s16x8*)&As[row * 64 + ((gbase ^ (row & 7)) << 3)];
            }
#pragma unroll
            for (int j = 0; j < 4; ++j) {
                int row = wn + j * 16 + (l & 15);
                bf[j] = *(const s16x8*)&Bs[row * 64 + ((gbase ^ (row & 7)) << 3)];
            }
#pragma unroll
            for (int i = 0; i < 4; ++i)
#pragma unroll
                for (int j = 0; j < 4; ++j)
                    acc[i][j] = __builtin_amdgcn_mfma_f32_16x16x32_bf16(af[i], bf[j], acc[i][j], 0, 0, 0);
        }
    }

    __syncthreads();
    const int col = l & 15, r4 = (l >> 4) * 4;
#pragma unroll
    for (int i = 0; i < 4; ++i)
#pragma unroll
        for (int j = 0; j < 4; ++j) {
            int n_l = wn + j * 16 + col;
            int m_b = wm + i * 16 + r4;
            u16x4 pk = {f2bf(acc[i][j][0]), f2bf(acc[i][j][1]),
                        f2bf(acc[i][j][2]), f2bf(acc[i][j][3])};
            *(u16x4*)&smem[n_l * 128 + (m_b ^ ((n_l & 15) << 3))] = pk;
        }
    __syncthreads();
    u16* sTb = simP + (size_t)khalf * 4194304 + (size_t)b * 512 * 512;
    {
        int n_l = t >> 1;
#pragma unroll
        for (int rep = 0; rep < 8; ++rep) {
            int c0 = (((t & 1) + rep * 2) << 3);
            s16x8 v = *(const s16x8*)&smem[n_l * 128 + (c0 ^ ((n_l & 15) << 3))];
            *(s16x8*)&sTb[(size_t)(n0 + n_l) * 512 + m0 + c0] = v;
        }
    }
}

// ================================================================ FINISH (single-pass, proven R2)
__global__ __launch_bounds__(256) void finish_kernel(const u16* __restrict__ p0,
                                                     const u16* __restrict__ p1,
                                                     const float* __restrict__ rm,
                                                     u16* __restrict__ attnT) {
    __shared__ float rml[32 * 513];
    __shared__ float scr[256];
    const int t = threadIdx.x;
    const int b = blockIdx.x >> 4, c0 = (blockIdx.x & 15) * 32;
    const int cl = t & 31, g = t >> 5;
    const float scale = 0.04419417382415922f;   // 512^-0.5

    for (int idx = t; idx < 32 * 512; idx += 256) {
        int c_l = idx >> 9, d = idx & 511;
        rml[c_l * 513 + d] = rm[(size_t)(c0 + c_l) * 512 + d];
    }
    __syncthreads();

    const u16* q0 = p0 + (size_t)b * 262144 + c0 + cl;
    const u16* q1 = p1 + (size_t)b * 262144 + c0 + cl;
    u16* ap = attnT + (size_t)b * 262144 + c0 + cl;
    const float* rp = &rml[cl * 513];

    float e[64];
    float s = 0.f;
#pragma unroll
    for (int dd = 0; dd < 64; ++dd) {
        int d = g * 64 + dd;
        float v = (bf2f(q0[(size_t)d * 512]) + bf2f(q1[(size_t)d * 512])) * scale + rp[d];
        e[dd] = __expf(v);
        s += e[dd];
    }
    scr[t] = s;
    __syncthreads();
    float tot = 0.f;
#pragma unroll
    for (int k = 0; k < 8; ++k) tot += scr[k * 32 + cl];
    float inv = 1.f / tot;
#pragma unroll
    for (int dd = 0; dd < 64; ++dd) {
        int d = g * 64 + dd;
        ap[(size_t)d * 512] = f2bf(e[dd] * inv);
    }
}

// ================================================================ CONV, 8-phase schedule + XCD-chunked swizzle
// Identical schedule to R5 (T2+T3+T4+T5, 3-deep pipeline, vmcnt(6) counted waits).
// ONLY change vs R5: 1-D grid of 256 with explicit XCD-chunked placement — hardware
// round-robins linear wg id over 8 XCDs, so decode xcd = id&7, slot = id>>3:
// each XCD owns TWO complete batches (slot>>4 picks which, slot&15 -> 4x4 m,n
// tiles). Per-XCD L2 working set: 2 x 1.18 MB xT + wA (4-way m-reuse) ~ 7 MB,
// vs R5's all-16-batches-per-XCD thrash (FETCH 107.9 MB, 3.4x over-fetch).
// (R6 resubmission: bench infra failed; kernel unchanged.)
__global__ __launch_bounds__(512) void conv_8ph(const u16* __restrict__ wA,
                                                const u16* __restrict__ xT,
                                                u16* __restrict__ vT) {
    __shared__ __attribute__((aligned(16))) u16 smem[73728];   // 3 x (A 8192 + B 16384) u16
    const int flat = blockIdx.x;
    const int xcd = flat & 7, slot = flat >> 3;
    const int b = 2 * xcd + (slot >> 4);
    const int s = slot & 15;
    const int m0 = (s >> 2) * 128, n0 = (s & 3) * 256;
    const int t = threadIdx.x, w = t >> 6, l = t & 63;
    const u16* xTb = xT + (size_t)b * 1156 * 512;

    // ---- staging addressing (per-thread, XOR-preswizzled source; LDS dest linear)
    const u16* agp[2];
    int pbb[4], giB[4];
#pragma unroll
    for (int i = 0; i < 2; ++i) {
        int rr = i * 64 + w * 8 + (l >> 3);
        int gi = (l & 7) ^ (rr & 7);
        agp[i] = wA + (size_t)(m0 + rr) * 4608 + gi * 8;
    }
#pragma unroll
    for (int i = 0; i < 4; ++i) {
        int rr = i * 64 + w * 8 + (l >> 3);
        int n = n0 + rr;
        pbb[i] = (n >> 5) * 34 + (n & 31);
        giB[i] = (l & 7) ^ (rr & 7);
    }

    // stage one full K-tile (6 gload_lds/thread: A0 A1 B0 B1 B2 B3)
    auto stage_tile = [&](int kt, u16* dA, u16* dB) {
        int r = kt >> 3, ci0 = (kt & 7) << 6;
        int rd3 = (r * 11) >> 5;
        int poff = rd3 * 34 + (r - rd3 * 3);
        int aofs = r * 512 + ci0;
        gload_lds16(agp[0] + aofs, dA + (w * 8) * 64);
        gload_lds16(agp[1] + aofs, dA + (64 + w * 8) * 64);
        gload_lds16(xTb + (size_t)(pbb[0] + poff) * 512 + ci0 + giB[0] * 8, dB + (w * 8) * 64);
        gload_lds16(xTb + (size_t)(pbb[1] + poff) * 512 + ci0 + giB[1] * 8, dB + (64 + w * 8) * 64);
        gload_lds16(xTb + (size_t)(pbb[2] + poff) * 512 + ci0 + giB[2] * 8, dB + (128 + w * 8) * 64);
        gload_lds16(xTb + (size_t)(pbb[3] + poff) * 512 + ci0 + giB[3] * 8, dB + (192 + w * 8) * 64);
    };

    // prologue: tiles 0 and 1 (12 loads in flight)
    stage_tile(0, smem, smem + 8192);
    stage_tile(1, smem + 24576, smem + 24576 + 8192);

    f32x4 acc[4][4] = {};
    const int wmo = (w >> 2) * 64, wno = (w & 3) * 64;
    const int lr = l & 15, gb0 = l >> 4;

    int cur = 0;
    for (int j = 0; j < 72; ++j) {
        int stg = cur + 2; if (stg >= 3) stg -= 3;
        u16* cA = smem + cur * 24576;
        u16* cB = cA + 8192;
        u16* sA = smem + stg * 24576;
        u16* sB = sA + 8192;
        const bool dost = (j + 2) < 72;
        int ci02 = 0, poff2 = 0, aofs2 = 0;
        if (dost) {
            int kt2 = j + 2;
            int r2 = kt2 >> 3; ci02 = (kt2 & 7) << 6;
            int rd3 = (r2 * 11) >> 5;
            poff2 = rd3 * 34 + (r2 - rd3 * 3);
            aofs2 = r2 * 512 + ci02;
        }

        // ---- tile boundary: wait tile j's 6 loads (tile j+1's stay in flight)
        if (j < 71) asm volatile("s_waitcnt vmcnt(6)" ::: "memory");
        else        asm volatile("s_waitcnt vmcnt(0)" ::: "memory");
        __builtin_amdgcn_s_barrier();

        s16x8 af[4][2], bf[4][2];
        // ================= PHASE A: read A-frags + B nj{0,1}; stage A0,A1,B0; MFMA nj{0,1}
#pragma unroll
        for (int mi = 0; mi < 4; ++mi) {
            int row = wmo + mi * 16 + lr;
#pragma unroll
            for (int ks = 0; ks < 2; ++ks)
                af[mi][ks] = *(const s16x8*)&cA[row * 64 + (((ks * 4 + gb0) ^ (row & 7)) << 3)];
        }
#pragma unroll
        for (int q = 0; q < 2; ++q) {
            int row = wno + q * 16 + lr;
#pragma unroll
            for (int ks = 0; ks < 2; ++ks)
                bf[q][ks] = *(const s16x8*)&cB[row * 64 + (((ks * 4 + gb0) ^ (row & 7)) << 3)];
        }
        if (dost) {
            gload_lds16(agp[0] + aofs2, sA + (w * 8) * 64);
            gload_lds16(agp[1] + aofs2, sA + (64 + w * 8) * 64);
            gload_lds16(xTb + (size_t)(pbb[0] + poff2) * 512 + ci02 + giB[0] * 8, sB + (w * 8) * 64);
        }
        __builtin_amdgcn_s_barrier();
        __builtin_amdgcn_s_setprio(1);
#pragma unroll
        for (int ks = 0; ks < 2; ++ks)
#pragma unroll
            for (int q = 0; q < 2; ++q)
#pragma unroll
                for (int mi = 0; mi < 4; ++mi)
                    acc[mi][q] = __builtin_amdgcn_mfma_f32_16x16x32_bf16(af[mi][ks], bf[q][ks], acc[mi][q], 0, 0, 0);
        __builtin_amdgcn_s_setprio(0);
        __builtin_amdgcn_s_barrier();

        // ================= PHASE B: read B nj{2,3}; stage B1,B2,B3; MFMA nj{2,3}
#pragma unroll
        for (int q = 2; q < 4; ++q) {
            int row = wno + q * 16 + lr;
#pragma unroll
            for (int ks = 0; ks < 2; ++ks)
                bf[q][ks] = *(const s16x8*)&cB[row * 64 + (((ks * 4 + gb0) ^ (row & 7)) << 3)];
        }
        if (dost) {
            gload_lds16(xTb + (size_t)(pbb[1] + poff2) * 512 + ci02 + giB[1] * 8, sB + (64 + w * 8) * 64);
            gload_lds16(xTb + (size_t)(pbb[2] + poff2) * 512 + ci02 + giB[2] * 8, sB + (128 + w * 8) * 64);
            gload_lds16(xTb + (size_t)(pbb[3] + poff2) * 512 + ci02 + giB[3] * 8, sB + (192 + w * 8) * 64);
        }
        __builtin_amdgcn_s_barrier();
        __builtin_amdgcn_s_setprio(1);
#pragma unroll
        for (int ks = 0; ks < 2; ++ks)
#pragma unroll
            for (int q = 2; q < 4; ++q)
#pragma unroll
                for (int mi = 0; mi < 4; ++mi)
                    acc[mi][q] = __builtin_amdgcn_mfma_f32_16x16x32_bf16(af[mi][ks], bf[q][ks], acc[mi][q], 0, 0, 0);
        __builtin_amdgcn_s_setprio(0);
        __builtin_amdgcn_s_barrier();

        cur += 1; if (cur >= 3) cur -= 3;
    }

    // ---- epilogue: acc -> LDS (XOR-swizzled 256x128) -> coalesced vT store
    __syncthreads();
    const int col = l & 15, r4 = (l >> 4) * 4;
#pragma unroll
    for (int mi = 0; mi < 4; ++mi)
#pragma unroll
        for (int nj = 0; nj < 4; ++nj) {
            int n_l = wno + nj * 16 + col;
            int co_b = wmo + mi * 16 + r4;
            u16x4 pk = {f2bf(acc[mi][nj][0]), f2bf(acc[mi][nj][1]),
                        f2bf(acc[mi][nj][2]), f2bf(acc[mi][nj][3])};
            *(u16x4*)&smem[n_l * 128 + (co_b ^ ((n_l & 15) << 3))] = pk;
        }
    __syncthreads();
    u16* vTb = vT + (size_t)b * 1024 * 512;
    {
        int n_l = t >> 1;
#pragma unroll
        for (int rep = 0; rep < 8; ++rep) {
            int c0 = (((t & 1) + rep * 2) << 3);
            s16x8 v = *(const s16x8*)&smem[n_l * 128 + (c0 ^ ((n_l & 15) << 3))];
            *(s16x8*)&vTb[(size_t)(n0 + n_l) * 512 + m0 + c0] = v;
        }
    }
}

// ================================================================ generic bf16 MFMA NT GEMM (proven)
// MODE 1: bf16 out (wattn); MODE 2: f32 out (final)
template <int MODE>
__global__ __launch_bounds__(256) void gemm_nt(const u16* __restrict__ A, size_t sA,
                                               const u16* __restrict__ B, size_t sB,
                                               void* __restrict__ Cv, size_t sC,
                                               int K, int ldc) {
    __shared__ __attribute__((aligned(16))) u16 As[128 * 64];
    __shared__ __attribute__((aligned(16))) u16 Bs[128 * 64];
    const int b = blockIdx.z, m0 = blockIdx.y * 128, n0 = blockIdx.x * 128;
    const int t = threadIdx.x, w = t >> 6, l = t & 63;
    const u16* Ab = A + (size_t)b * sA;
    const u16* Bb = B + (size_t)b * sB;

    const u16 *agp[4], *bgp[4];
    u16 *ald[4], *bld[4];
#pragma unroll
    for (int i = 0; i < 4; ++i) {
        int rr = w * 8 + i * 32 + (l >> 3);
        int gi = (l & 7) ^ (rr & 7);
        agp[i] = Ab + (size_t)(m0 + rr) * K + gi * 8;
        bgp[i] = Bb + (size_t)(n0 + rr) * K + gi * 8;
        ald[i] = &As[(w * 8 + i * 32) * 64];
        bld[i] = &Bs[(w * 8 + i * 32) * 64];
    }

    f32x4 acc[4][4] = {};
    const int wm = (w >> 1) * 64, wn = (w & 1) * 64;
    const int nkt = K >> 6;
    for (int kt = 0; kt < nkt; ++kt) {
        int ko = kt << 6;
        if (kt) __syncthreads();
#pragma unroll
        for (int i = 0; i < 4; ++i) gload_lds16(agp[i] + ko, ald[i]);
#pragma unroll
        for (int i = 0; i < 4; ++i) gload_lds16(bgp[i] + ko, bld[i]);
        __syncthreads();
#pragma unroll
        for (int kk = 0; kk < 2; ++kk) {
            int gbase = kk * 4 + (l >> 4);
            s16x8 af[4], bf[4];
#pragma unroll
            for (int i = 0; i < 4; ++i) {
                int row = wm + i * 16 + (l & 15);
                af[i] = *(const s16x8*)&As[row * 64 + ((gbase ^ (row & 7)) << 3)];
            }
#pragma unroll
            for (int j = 0; j < 4; ++j) {
                int row = wn + j * 16 + (l & 15);
                bf[j] = *(const s16x8*)&Bs[row * 64 + ((gbase ^ (row & 7)) << 3)];
            }
#pragma unroll
            for (int i = 0; i < 4; ++i)
#pragma unroll
                for (int j = 0; j < 4; ++j)
                    acc[i][j] = __builtin_amdgcn_mfma_f32_16x16x32_bf16(af[i], bf[j], acc[i][j], 0, 0, 0);
        }
    }

    const int col = l & 15, r4 = (l >> 4) * 4;
#pragma unroll
    for (int i = 0; i < 4; ++i)
#pragma unroll
        for (int j = 0; j < 4; ++j)
#pragma unroll
            for (int reg = 0; reg < 4; ++reg) {
                int m = m0 + wm + i * 16 + r4 + reg;
                int n = n0 + wn + j * 16 + col;
                if (MODE == 1) {
                    u16* C = (u16*)Cv + (size_t)b * sC;
                    C[(size_t)m * ldc + n] = f2bf(acc[i][j][reg]);
                } else {
                    float* C = (float*)Cv + (size_t)b * sC;
                    C[(size_t)m * ldc + n] = acc[i][j][reg];
                }
            }
}

// ----------------------------------------------------------------
extern "C" void kernel_launch(void* const* d_in, const int* in_sizes, int n_in,
                              void* d_out, int out_size, void* d_ws, size_t ws_size,
                              hipStream_t stream) {
    (void)in_sizes; (void)n_in; (void)out_size; (void)ws_size;
    const float* x1 = (const float*)d_in[0];
    const float* x2 = (const float*)d_in[1];
    const float* gw = (const float*)d_in[2];
    const float* ww = (const float*)d_in[3];
    const float* w1 = (const float*)d_in[4];
    const float* w2 = (const float*)d_in[5];
    float* out = (float*)d_out;
    float* ws = (float*)d_ws;

    u16* xT    = (u16*)(ws + OFF_XT);
    u16* xq    = (u16*)(ws + OFF_XQ);
    u16* attnT = (u16*)(ws + OFF_ATTNT);   // after xq dies
    u16* wattn = (u16*)(ws + OFF_WATTN);
    u16* simP  = (u16*)(ws + OFF_P0);      // p0; p1 at +4,194,304 u16
    u16* p0    = (u16*)(ws + OFF_P0);
    u16* p1    = (u16*)(ws + OFF_P1);
    u16* vT    = (u16*)(ws + OFF_VT);      // after p0/p1 die
    u16* wA    = (u16*)(ws + OFF_WA);
    float* rm  = ws + OFF_RM;
    u16* wwb   = (u16*)(ws + OFF_WWB);

    prep_kernel<<<3728, 256, 0, stream>>>(x1, x2, gw, ww, w1, w2, rm, wA, wwb, xT, xq);
    // p{0,1}[b][d][c] = partial QQ^T halves (512 blocks, 2/CU)
    sim_part<<<dim3(8, 4, 16), 256, 0, stream>>>(xq, simP);
    // attnT[b][d][c] = softmax over d of ((p0+p1)*scale + rm[c][d])
    finish_kernel<<<256, 256, 0, stream>>>(p0, p1, rm, attnT);
    // wattn[b][o][d] = sum_c wwb[o][c] * attnT[b][d][c]  (bf16 out)
    gemm_nt<1><<<dim3(4, 2, 16), 256, 0, stream>>>(
        wwb, 0, attnT, (size_t)512 * 512, wattn, (size_t)256 * 512, 512, 512);
    // conv, 8-phase pipelined: 256 blocks 1-D (XCD-chunked: 2 batches per XCD), 512 thr
    conv_8ph<<<256, 512, 0, stream>>>(wA, xT, vT);
    // out[b][o][n] = sum_d wattn[b][o][d] * vT[b][n][d]  (f32 out)
    gemm_nt<2><<<dim3(8, 2, 16), 256, 0, stream>>>(
        wattn, (size_t)256 * 512, vT, (size_t)1024 * 512, out, (size_t)256 * 1024, 512, 1024);
}